// Round 9
// baseline (317.727 us; speedup 1.0000x reference)
//
#include <hip/hip_runtime.h>

#define T_TOK 4096
#define DIM   1024
#define FFD   2048
#define NEXP  4
#define NRP   9216      // 36*256 padded row capacity (256-aligned expert buckets)
#define NTILES 36

typedef unsigned short u16;
typedef __attribute__((ext_vector_type(8))) short short8;
typedef __attribute__((ext_vector_type(4))) float f32x4;
typedef __attribute__((ext_vector_type(8))) unsigned short u16x8;
typedef __attribute__((ext_vector_type(4))) unsigned short u16x4;

typedef __attribute__((address_space(1))) unsigned int as1_u32;
typedef __attribute__((address_space(3))) unsigned int as3_u32;

__device__ __forceinline__ u16 f2bf(float f) {
  union { float f; unsigned u; } v; v.f = f;
  unsigned u = v.u;
  return (u16)((u + 0x7fffu + ((u >> 16) & 1u)) >> 16);   // RNE
}
__device__ __forceinline__ float bf2f(u16 h) {
  union { unsigned u; float f; } v; v.u = ((unsigned)h) << 16;
  return v.f;
}
__device__ __forceinline__ void gload16(const void* g, void* l) {
  __builtin_amdgcn_global_load_lds((const as1_u32*)g, (as3_u32*)l, 16, 0, 0);
}

// ---------------- router: fp32 logits, softmax top-2, renorm ----------------
__global__ void router_k(const float* __restrict__ x, const float* __restrict__ gw,
                         float* __restrict__ logits_out, int* __restrict__ sel,
                         float* __restrict__ selw) {
  int t = blockIdx.x;
  int lane = threadIdx.x;           // block = 64 (one wave)
  float xv[16];
#pragma unroll
  for (int i = 0; i < 16; ++i) xv[i] = x[(size_t)t * DIM + lane + i * 64];
  float l[4];
#pragma unroll
  for (int e = 0; e < 4; ++e) {
    float s = 0.f;
#pragma unroll
    for (int i = 0; i < 16; ++i) s += xv[i] * gw[e * DIM + lane + i * 64];
#pragma unroll
    for (int off = 32; off > 0; off >>= 1) s += __shfl_xor(s, off, 64);
    l[e] = s;
  }
  if (lane == 0) {
#pragma unroll
    for (int e = 0; e < 4; ++e) logits_out[(size_t)t * 4 + e] = l[e];
    int e0 = 0; float b0 = l[0];
    for (int e = 1; e < 4; ++e) if (l[e] > b0) { b0 = l[e]; e0 = e; }
    int e1 = -1; float b1 = -3.4e38f;
    for (int e = 0; e < 4; ++e) if (e != e0 && l[e] > b1) { b1 = l[e]; e1 = e; }
    float p1 = expf(b1 - b0);
    float w0 = 1.f / (1.f + p1);
    sel[2 * t] = e0; sel[2 * t + 1] = e1;
    selw[2 * t] = w0; selw[2 * t + 1] = 1.f - w0;
  }
}

// ------------- deterministic bucket assignment (single block) ---------------
__global__ void scan_k(const int* __restrict__ sel, int* __restrict__ pos,
                       int* __restrict__ offs, int* __restrict__ rowtok,
                       int* __restrict__ pairrow) {
  __shared__ int base[4];
  __shared__ int wsum[16][4];
  __shared__ int off_s[5];
  int tid = threadIdx.x, lane = tid & 63, wid = tid >> 6;   // 1024 threads = 16 waves
  if (tid < 4) base[tid] = 0;
  __syncthreads();
  for (int chunk = 0; chunk < 4; ++chunk) {
    int t = chunk * 1024 + tid;
    int e0 = sel[2 * t], e1 = sel[2 * t + 1];
    unsigned long long ltm = (1ull << lane) - 1ull;
    bool f[4]; int within[4];
#pragma unroll
    for (int e = 0; e < 4; ++e) {
      f[e] = (e0 == e) || (e1 == e);
      unsigned long long m = __ballot(f[e]);
      within[e] = __popcll(m & ltm);
      if (lane == 0) wsum[wid][e] = __popcll(m);
    }
    __syncthreads();
    int wbase[4] = {0, 0, 0, 0}, tot[4] = {0, 0, 0, 0};
    for (int i = 0; i < 16; ++i)
#pragma unroll
      for (int e = 0; e < 4; ++e) {
        int v = wsum[i][e];
        if (i < wid) wbase[e] += v;
        tot[e] += v;
      }
#pragma unroll
    for (int e = 0; e < 4; ++e)
      if (f[e]) {
        int p = base[e] + wbase[e] + within[e];
        if (e0 == e) pos[2 * t] = p; else pos[2 * t + 1] = p;
      }
    __syncthreads();
    if (tid < 4) base[tid] += tot[tid];
    __syncthreads();
  }
  if (tid == 0) {
    int o = 0;
    for (int e = 0; e < 4; ++e) { off_s[e] = o; o += ((base[e] + 255) >> 8) << 8; }  // 256-align
    off_s[4] = o;
    for (int i = 0; i < 5; ++i) offs[i] = off_s[i];
  }
  __syncthreads();
  for (int r = tid; r < NRP; r += 1024) rowtok[r] = -1;
  __syncthreads();
  for (int t = tid; t < T_TOK; t += 1024) {
#pragma unroll
    for (int s = 0; s < 2; ++s) {
      int e = sel[2 * t + s];
      int rr = off_s[e] + pos[2 * t + s];
      pairrow[2 * t + s] = rr;
      rowtok[rr] = t;
    }
  }
}

// ---------------- gather x rows (bucket order) -> bf16 ----------------------
__global__ void gather_k(const float* __restrict__ x, const int* __restrict__ rowtok,
                         u16* __restrict__ xg) {
  int r = blockIdx.x, tid = threadIdx.x;   // 256 threads, 4 floats each
  int t = rowtok[r];
  float4 v = make_float4(0.f, 0.f, 0.f, 0.f);
  if (t >= 0) v = ((const float4*)(x + (size_t)t * DIM))[tid];
  u16x4 o;
  o[0] = f2bf(v.x); o[1] = f2bf(v.y); o[2] = f2bf(v.z); o[3] = f2bf(v.w);
  ((u16x4*)(xg + (size_t)r * DIM))[tid] = o;
}

// -------- pre-convert LoRA A matrices to bf16 (abgu[4][32][1024], adb[4][16][2048])
__global__ void cvtA_k(const float* __restrict__ Ag, const float* __restrict__ Au,
                       const float* __restrict__ Ad, u16* __restrict__ abgu,
                       u16* __restrict__ adb) {
  int g = blockIdx.x * 256 + threadIdx.x;   // each handles 4 elements
  if (g < 32768) {
    int flat = g * 4;
    int e = flat >> 15;
    int rem = flat & 32767;
    int q = rem >> 10;
    int d = rem & 1023;
    const float* src = (q < 16) ? (Ag + ((size_t)e * 16 + q) * DIM + d)
                                : (Au + ((size_t)e * 16 + (q - 16)) * DIM + d);
    float4 v = *(const float4*)src;
    u16x4 o; o[0] = f2bf(v.x); o[1] = f2bf(v.y); o[2] = f2bf(v.z); o[3] = f2bf(v.w);
    *(u16x4*)(abgu + (size_t)flat) = o;
  } else {
    int flat = (g - 32768) * 4;
    float4 v = *(const float4*)(Ad + flat);
    u16x4 o; o[0] = f2bf(v.x); o[1] = f2bf(v.y); o[2] = f2bf(v.z); o[3] = f2bf(v.w);
    *(u16x4*)(adb + (size_t)flat) = o;
  }
}

// ---------------- per-row LoRA A-projections, 2 rows per wave ----------------
__global__ void xa_k(const u16* __restrict__ xg, const u16* __restrict__ abgu,
                     const int* __restrict__ offs, float* __restrict__ xagu) {
  int r0 = blockIdx.x * 2, lane = threadIdx.x;   // block = 64
  int e = 0;
  if (r0 >= offs[1]) e = 1;
  if (r0 >= offs[2]) e = 2;
  if (r0 >= offs[3]) e = 3;
  float x0[16], x1[16];
#pragma unroll
  for (int i = 0; i < 4; ++i) {
    u16x4 v0 = ((const u16x4*)(xg + (size_t)r0 * DIM))[lane + i * 64];
    u16x4 v1 = ((const u16x4*)(xg + (size_t)(r0 + 1) * DIM))[lane + i * 64];
#pragma unroll
    for (int j = 0; j < 4; ++j) { x0[i * 4 + j] = bf2f(v0[j]); x1[i * 4 + j] = bf2f(v1[j]); }
  }
  const u16* A = abgu + (size_t)e * 32 * DIM;
  for (int q = 0; q < 32; ++q) {
    float s0 = 0.f, s1 = 0.f;
#pragma unroll
    for (int i = 0; i < 4; ++i) {
      u16x4 av = ((const u16x4*)(A + (size_t)q * DIM))[lane + i * 64];
#pragma unroll
      for (int j = 0; j < 4; ++j) {
        float a = bf2f(av[j]);
        s0 += x0[i * 4 + j] * a; s1 += x1[i * 4 + j] * a;
      }
    }
#pragma unroll
    for (int off = 32; off > 0; off >>= 1) { s0 += __shfl_xor(s0, off, 64); s1 += __shfl_xor(s1, off, 64); }
    if (lane == 0) { xagu[(size_t)r0 * 32 + q] = s0; xagu[(size_t)(r0 + 1) * 32 + q] = s1; }
  }
}

__global__ void aad_k(const u16* __restrict__ act, const u16* __restrict__ adb,
                      const int* __restrict__ offs, float* __restrict__ aad) {
  int r0 = blockIdx.x * 2, lane = threadIdx.x;
  int e = 0;
  if (r0 >= offs[1]) e = 1;
  if (r0 >= offs[2]) e = 2;
  if (r0 >= offs[3]) e = 3;
  float x0[32], x1[32];
#pragma unroll
  for (int i = 0; i < 8; ++i) {
    u16x4 v0 = ((const u16x4*)(act + (size_t)r0 * FFD))[lane + i * 64];
    u16x4 v1 = ((const u16x4*)(act + (size_t)(r0 + 1) * FFD))[lane + i * 64];
#pragma unroll
    for (int j = 0; j < 4; ++j) { x0[i * 4 + j] = bf2f(v0[j]); x1[i * 4 + j] = bf2f(v1[j]); }
  }
  const u16* A = adb + (size_t)e * 16 * FFD;
  for (int q = 0; q < 16; ++q) {
    float s0 = 0.f, s1 = 0.f;
#pragma unroll
    for (int i = 0; i < 8; ++i) {
      u16x4 av = ((const u16x4*)(A + (size_t)q * FFD))[lane + i * 64];
#pragma unroll
      for (int j = 0; j < 4; ++j) {
        float a = bf2f(av[j]);
        s0 += x0[i * 4 + j] * a; s1 += x1[i * 4 + j] * a;
      }
    }
#pragma unroll
    for (int off = 32; off > 0; off >>= 1) { s0 += __shfl_xor(s0, off, 64); s1 += __shfl_xor(s1, off, 64); }
    if (lane == 0) { aad[(size_t)r0 * 16 + q] = s0; aad[(size_t)(r0 + 1) * 16 + q] = s1; }
  }
}

// ---------------- weight transpose fp32[K][N] -> bf16[N][K] ------------------
__global__ void transpose_k(const float* __restrict__ in, u16* __restrict__ out,
                            int K, int N) {
  int e = blockIdx.z;
  int n0 = blockIdx.x * 32, k0 = blockIdx.y * 32;
  const float* I = in + (size_t)e * K * N;
  u16* O = out + (size_t)e * N * K;
  __shared__ u16 tile[32][33];
#pragma unroll
  for (int i = 0; i < 4; ++i) {
    int k = k0 + threadIdx.y + i * 8;
    tile[threadIdx.y + i * 8][threadIdx.x] = f2bf(I[(size_t)k * N + n0 + threadIdx.x]);
  }
  __syncthreads();
#pragma unroll
  for (int i = 0; i < 4; ++i) {
    int n = n0 + threadIdx.y + i * 8;
    O[(size_t)n * K + k0 + threadIdx.x] = tile[threadIdx.x][threadIdx.y + i * 8];
  }
}

// =============== GEMM1: 256x256 tile, 4 waves each 128x128 ==================
// 16 ds_read_b128 per 64 MFMA per wave-step (0.25 reads/MFMA). Register
// double-buffered fragments: reads(t+1) issue, then MFMA(t) from last step's
// regs -> LDS-read latency hides under the 64-MFMA cluster. 3 staging bufs
// (96KB), vmcnt(8) counted wait BEFORE the single per-step barrier.
__global__ __launch_bounds__(256, 1) void gemm1_k(
    const u16* __restrict__ xg, const u16* __restrict__ wgu_t,
    const float* __restrict__ gub, const float* __restrict__ Bg,
    const float* __restrict__ Bu, const float* __restrict__ xagu,
    const int* __restrict__ offs, u16* __restrict__ act) {
  __shared__ __align__(16) u16 sAB[65536];   // staging 3x16384; epilogue [256][256]
  int tid = threadIdx.x, w = tid >> 6, lane = tid & 63;
  int f0 = blockIdx.x * 128;                 // 128 f-cols
  int row0 = blockIdx.y * 256;
  int e = 0;
  if (row0 >= offs[1]) e = 1;
  if (row0 >= offs[2]) e = 2;
  if (row0 >= offs[3]) e = 3;
  int wm = w >> 1, wn = w & 1;

  int srow = lane >> 2;
  int scol = ((lane & 3) ^ ((lane >> 3) & 3)) * 8;     // pre-swizzled src granule (T2)
  const u16* gA = xg + (size_t)(row0 + w * 16 + srow) * DIM + scol;
  const u16* gBb = wgu_t + ((size_t)e << 22);
  const u16* gB01 = gBb + (size_t)(f0 + w * 16 + srow) * DIM + scol;          // gate chunks
  const u16* gB23 = gBb + (size_t)(2048 + f0 + w * 16 + srow) * DIM + scol;   // up chunks

  int fo = ((lane >> 4) ^ ((lane >> 1) & 3)) * 8;      // swizzled frag k-offset
  int ard = (wm * 128 + (lane & 15)) * 32 + fo;        // A-frag base (rel. buf), fr stride 512
  int brd = 8192 + (wn * 128 + (lane & 15)) * 32 + fo; // B-frag base, ni stride 512

  f32x4 acc[8][8];
#pragma unroll
  for (int i = 0; i < 8; ++i)
#pragma unroll
    for (int j = 0; j < 8; ++j) acc[i][j] = f32x4{0.f, 0.f, 0.f, 0.f};

  auto STAGE = [&](int k) {
    u16* dA = sAB + (k % 3) * 16384 + w * 512;
    const u16* a = gA + k * 32;
    gload16(a, dA);
    gload16(a + 64 * DIM, dA + 2048);
    gload16(a + 128 * DIM, dA + 4096);
    gload16(a + 192 * DIM, dA + 6144);
    u16* dB = sAB + (k % 3) * 16384 + 8192 + w * 512;
    const u16* b0 = gB01 + k * 32;
    const u16* b2 = gB23 + k * 32;
    gload16(b0, dB);
    gload16(b0 + 64 * DIM, dB + 2048);
    gload16(b2, dB + 4096);
    gload16(b2 + 64 * DIM, dB + 6144);
  };
  auto READS = [&](int k, short8* a8, short8* b8) {
    const u16* cb = sAB + (k % 3) * 16384;
#pragma unroll
    for (int fr = 0; fr < 8; ++fr) a8[fr] = *(const short8*)&cb[ard + fr * 512];
#pragma unroll
    for (int ni = 0; ni < 8; ++ni) b8[ni] = *(const short8*)&cb[brd + ni * 512];
  };
  auto MM = [&](short8* a8, short8* b8) {
#pragma unroll
    for (int fr = 0; fr < 8; ++fr)
#pragma unroll
      for (int ni = 0; ni < 8; ++ni)
        acc[fr][ni] = __builtin_amdgcn_mfma_f32_16x16x32_bf16(a8[fr], b8[ni], acc[fr][ni], 0, 0, 0);
  };

  short8 af0[8], bf0[8], af1[8], bf1[8];
  STAGE(0); STAGE(1);
  asm volatile("s_waitcnt vmcnt(8)" ::: "memory");
  __builtin_amdgcn_s_barrier();
  READS(0, af0, bf0);
#pragma unroll
  for (int t = 0; t < 32; ++t) {
    if (t < 30) STAGE(t + 2);
    if (t < 31) {
      if (t == 30) asm volatile("s_waitcnt vmcnt(0)" ::: "memory");
      else         asm volatile("s_waitcnt vmcnt(8)" ::: "memory");
      __builtin_amdgcn_s_barrier();
    }
    if (t & 1) {
      if (t < 31) READS(t + 1, af0, bf0);
      MM(af1, bf1);
    } else {
      if (t < 31) READS(t + 1, af1, bf1);
      MM(af0, bf0);
    }
  }

  // ---- LoRA + bias as one extra K=32 MFMA step ----
  // buf0.A rows = [2*xa_gate | 1@k16]; buf1.A = [2*xa_up | 1@k16];
  // buf0.B rows 0-127 = Bg+bias, 128-255 = Bu+bias.
  __syncthreads();
  {
    int r = tid;
    int key = (r >> 1) & 3;
    u16 one8[8] = {0x3f80, 0, 0, 0, 0, 0, 0, 0};
    u16 z8[8] = {0, 0, 0, 0, 0, 0, 0, 0};
#pragma unroll
    for (int h = 0; h < 2; ++h) {
      u16* A = sAB + h * 16384 + r * 32;
      u16 tmp[16];
#pragma unroll
      for (int q = 0; q < 16; ++q) tmp[q] = f2bf(2.f * xagu[(size_t)(row0 + r) * 32 + h * 16 + q]);
      *(u16x8*)&A[(0 ^ key) * 8] = *(u16x8*)&tmp[0];
      *(u16x8*)&A[(1 ^ key) * 8] = *(u16x8*)&tmp[8];
      *(u16x8*)&A[(2 ^ key) * 8] = *(u16x8*)&one8[0];
      *(u16x8*)&A[(3 ^ key) * 8] = *(u16x8*)&z8[0];
    }
    u16* B = sAB + 8192 + r * 32;
    const float* Bsrc = (r < 128) ? Bg : Bu;
    int fb = r & 127;
    float bias = gub[e * 4096 + ((r < 128) ? (f0 + fb) : (2048 + f0 + fb))];
    u16 tb[16];
#pragma unroll
    for (int q = 0; q < 16; ++q) tb[q] = f2bf(Bsrc[((size_t)e * FFD + f0 + fb) * 16 + q]);
    u16 bb8[8] = {f2bf(bias), 0, 0, 0, 0, 0, 0, 0};
    *(u16x8*)&B[(0 ^ key) * 8] = *(u16x8*)&tb[0];
    *(u16x8*)&B[(1 ^ key) * 8] = *(u16x8*)&tb[8];
    *(u16x8*)&B[(2 ^ key) * 8] = *(u16x8*)&bb8[0];
    *(u16x8*)&B[(3 ^ key) * 8] = *(u16x8*)&z8[0];
  }
  __syncthreads();
  {
    const u16* ca = sAB + (wn ? 16384 : 0);
    short8 a8[8], b8[8];
#pragma unroll
    for (int fr = 0; fr < 8; ++fr) a8[fr] = *(const short8*)&ca[ard + fr * 512];
#pragma unroll
    for (int ni = 0; ni < 8; ++ni) b8[ni] = *(const short8*)&sAB[brd + ni * 512];
    MM(a8, b8);
  }
  // ---- SwiGLU via LDS exchange: [256][256] bf16, XOR bank-swizzled ----
  __syncthreads();
#pragma unroll
  for (int fr = 0; fr < 8; ++fr)
#pragma unroll
    for (int ni = 0; ni < 8; ++ni)
#pragma unroll
      for (int j = 0; j < 4; ++j) {
        int row = wm * 128 + fr * 16 + (lane >> 4) * 4 + j;
        int col = wn * 128 + ni * 16 + (lane & 15);
        int key = ((row & 3) ^ ((row >> 2) & 3)) << 4;
        sAB[row * 256 + (col ^ key)] = f2bf(acc[fr][ni][j]);
      }
  __syncthreads();
  {
    int fc = (tid & 15) * 8;
    int rb = tid >> 4;
#pragma unroll
    for (int it = 0; it < 16; ++it) {
      int row = rb + it * 16;
      int key = ((row & 3) ^ ((row >> 2) & 3)) << 4;
      u16x8 gv = *(const u16x8*)&sAB[row * 256 + (fc ^ key)];
      u16x8 uv = *(const u16x8*)&sAB[row * 256 + ((fc + 128) ^ key)];
      u16x8 ov;
#pragma unroll
      for (int j = 0; j < 8; ++j) {
        float g = bf2f(gv[j]);
        float u = bf2f(uv[j]);
        float s = g / (1.f + __expf(-g));
        ov[j] = f2bf(s * u);
      }
      *(u16x8*)(act + (size_t)(row0 + row) * FFD + f0 + fc) = ov;
    }
  }
}

// ========== GEMM2: 256x256 tile, 4 waves each 128x128, split-K=2 ============
__global__ __launch_bounds__(256, 1) void gemm2_k(
    const u16* __restrict__ act, const u16* __restrict__ wd_t,
    const float* __restrict__ db, const float* __restrict__ Bd,
    const float* __restrict__ aad, const int* __restrict__ offs,
    u16* __restrict__ down) {
  __shared__ __align__(16) u16 sAB[49152];
  int tid = threadIdx.x, w = tid >> 6, lane = tid & 63;
  int n0 = blockIdx.x * 256;
  int row0 = blockIdx.y * 256;
  int ks = blockIdx.z;
  size_t kbase = (size_t)ks * 1024;
  int e = 0;
  if (row0 >= offs[1]) e = 1;
  if (row0 >= offs[2]) e = 2;
  if (row0 >= offs[3]) e = 3;
  int wm = w >> 1, wn = w & 1;

  int srow = lane >> 2;
  int scol = ((lane & 3) ^ ((lane >> 3) & 3)) * 8;
  const u16* gA = act + (size_t)(row0 + w * 16 + srow) * FFD + kbase + scol;
  const u16* gB = wd_t + (size_t)e * DIM * FFD + (size_t)(n0 + w * 16 + srow) * FFD + kbase + scol;

  int fo = ((lane >> 4) ^ ((lane >> 1) & 3)) * 8;
  int ard = (wm * 128 + (lane & 15)) * 32 + fo;
  int brd = 8192 + (wn * 128 + (lane & 15)) * 32 + fo;

  f32x4 acc[8][8];
#pragma unroll
  for (int i = 0; i < 8; ++i)
#pragma unroll
    for (int j = 0; j < 8; ++j) acc[i][j] = f32x4{0.f, 0.f, 0.f, 0.f};

  auto STAGE = [&](int k) {
    u16* dA = sAB + (k % 3) * 16384 + w * 512;
    const u16* a = gA + k * 32;
    gload16(a, dA);
    gload16(a + 64 * FFD, dA + 2048);
    gload16(a + 128 * FFD, dA + 4096);
    gload16(a + 192 * FFD, dA + 6144);
    u16* dB = sAB + (k % 3) * 16384 + 8192 + w * 512;
    const u16* b = gB + k * 32;
    gload16(b, dB);
    gload16(b + 64 * FFD, dB + 2048);
    gload16(b + 128 * FFD, dB + 4096);
    gload16(b + 192 * FFD, dB + 6144);
  };
  auto READS = [&](int k, short8* a8, short8* b8) {
    const u16* cb = sAB + (k % 3) * 16384;
#pragma unroll
    for (int fr = 0; fr < 8; ++fr) a8[fr] = *(const short8*)&cb[ard + fr * 512];
#pragma unroll
    for (int ni = 0; ni < 8; ++ni) b8[ni] = *(const short8*)&cb[brd + ni * 512];
  };
  auto MM = [&](short8* a8, short8* b8) {
#pragma unroll
    for (int fr = 0; fr < 8; ++fr)
#pragma unroll
      for (int ni = 0; ni < 8; ++ni)
        acc[fr][ni] = __builtin_amdgcn_mfma_f32_16x16x32_bf16(a8[fr], b8[ni], acc[fr][ni], 0, 0, 0);
  };

  short8 af0[8], bf0[8], af1[8], bf1[8];
  STAGE(0); STAGE(1);
  asm volatile("s_waitcnt vmcnt(8)" ::: "memory");
  __builtin_amdgcn_s_barrier();
  READS(0, af0, bf0);
#pragma unroll
  for (int t = 0; t < 32; ++t) {
    if (t < 30) STAGE(t + 2);
    if (t < 31) {
      if (t == 30) asm volatile("s_waitcnt vmcnt(0)" ::: "memory");
      else         asm volatile("s_waitcnt vmcnt(8)" ::: "memory");
      __builtin_amdgcn_s_barrier();
    }
    if (t & 1) {
      if (t < 31) READS(t + 1, af0, bf0);
      MM(af1, bf1);
    } else {
      if (t < 31) READS(t + 1, af1, bf1);
      MM(af0, bf0);
    }
  }

  if (ks == 0) {
    // ---- LoRA-down + bias as one extra K=32 MFMA step ----
    __syncthreads();
    {
      int r = tid;
      int key = (r >> 1) & 3;
      u16 one8[8] = {0x3f80, 0, 0, 0, 0, 0, 0, 0};
      u16 z8[8] = {0, 0, 0, 0, 0, 0, 0, 0};
      u16* A = sAB + r * 32;
      u16 tmp[16];
#pragma unroll
      for (int q = 0; q < 16; ++q) tmp[q] = f2bf(2.f * aad[(size_t)(row0 + r) * 16 + q]);
      *(u16x8*)&A[(0 ^ key) * 8] = *(u16x8*)&tmp[0];
      *(u16x8*)&A[(1 ^ key) * 8] = *(u16x8*)&tmp[8];
      *(u16x8*)&A[(2 ^ key) * 8] = *(u16x8*)&one8[0];
      *(u16x8*)&A[(3 ^ key) * 8] = *(u16x8*)&z8[0];
      u16* B = sAB + 8192 + r * 32;
      u16 tb[16];
#pragma unroll
      for (int q = 0; q < 16; ++q) tb[q] = f2bf(Bd[((size_t)e * DIM + n0 + r) * 16 + q]);
      u16 bb8[8] = {f2bf(db[e * DIM + n0 + r]), 0, 0, 0, 0, 0, 0, 0};
      *(u16x8*)&B[(0 ^ key) * 8] = *(u16x8*)&tb[0];
      *(u16x8*)&B[(1 ^ key) * 8] = *(u16x8*)&tb[8];
      *(u16x8*)&B[(2 ^ key) * 8] = *(u16x8*)&bb8[0];
      *(u16x8*)&B[(3 ^ key) * 8] = *(u16x8*)&z8[0];
    }
    __syncthreads();
    {
      short8 a8[8], b8[8];
#pragma unroll
      for (int fr = 0; fr < 8; ++fr) a8[fr] = *(const short8*)&sAB[ard + fr * 512];
#pragma unroll
      for (int ni = 0; ni < 8; ++ni) b8[ni] = *(const short8*)&sAB[brd + ni * 512];
      MM(a8, b8);
    }
  }
  // ---- store bf16 partial ----
#pragma unroll
  for (int fr = 0; fr < 8; ++fr)
#pragma unroll
    for (int ni = 0; ni < 8; ++ni)
#pragma unroll
      for (int j = 0; j < 4; ++j) {
        int lr = wm * 128 + fr * 16 + (lane >> 4) * 4 + j;
        int lc = wn * 128 + ni * 16 + (lane & 15);
        down[((size_t)ks * NRP + row0 + lr) * DIM + n0 + lc] = f2bf(acc[fr][ni][j]);
      }
}

// ---------------- weighted combine (sums split-K halves) --------------------
__global__ void combine_k(const u16* __restrict__ down, const int* __restrict__ pairrow,
                          const float* __restrict__ selw, float* __restrict__ out) {
  int t = blockIdx.x, tid = threadIdx.x;   // 256 threads, 4 cols each
  int r0 = pairrow[2 * t], r1 = pairrow[2 * t + 1];
  float w0 = selw[2 * t], w1 = selw[2 * t + 1];
  u16x4 a0 = *(const u16x4*)(down + ((size_t)r0) * DIM + tid * 4);
  u16x4 a1 = *(const u16x4*)(down + ((size_t)NRP + r0) * DIM + tid * 4);
  u16x4 b0 = *(const u16x4*)(down + ((size_t)r1) * DIM + tid * 4);
  u16x4 b1 = *(const u16x4*)(down + ((size_t)NRP + r1) * DIM + tid * 4);
  f32x4 o;
#pragma unroll
  for (int j = 0; j < 4; ++j)
    o[j] = w0 * (bf2f(a0[j]) + bf2f(a1[j])) + w1 * (bf2f(b0[j]) + bf2f(b1[j]));
  *(f32x4*)(out + (size_t)t * DIM + tid * 4) = o;
}

extern "C" void kernel_launch(void* const* d_in, const int* in_sizes, int n_in,
                              void* d_out, int out_size, void* d_ws, size_t ws_size,
                              hipStream_t stream) {
  const float* x         = (const float*)d_in[0];
  const float* gate_w    = (const float*)d_in[1];
  const float* gate_up_w = (const float*)d_in[2];
  const float* gate_up_b = (const float*)d_in[3];
  const float* down_w    = (const float*)d_in[4];
  const float* down_b    = (const float*)d_in[5];
  const float* A_gate    = (const float*)d_in[6];
  const float* B_gate    = (const float*)d_in[7];
  const float* A_up      = (const float*)d_in[8];
  const float* B_up      = (const float*)d_in[9];
  const float* A_down    = (const float*)d_in[10];
  const float* B_down    = (const float*)d_in[11];

  float* out_final  = (float*)d_out;
  float* out_logits = out_final + (size_t)T_TOK * DIM;

  char* ws = (char*)d_ws;
  size_t o = 0;
  auto take = [&](size_t bytes) -> void* {
    void* p = ws + o;
    o = (o + bytes + 255) & ~(size_t)255;
    return p;
  };
  int*   offs    = (int*)take(64);
  int*   sel     = (int*)take((size_t)T_TOK * 2 * 4);
  float* selw    = (float*)take((size_t)T_TOK * 2 * 4);
  int*   pos     = (int*)take((size_t)T_TOK * 2 * 4);
  int*   pairrow = (int*)take((size_t)T_TOK * 2 * 4);
  int*   rowtok  = (int*)take((size_t)NRP * 4);
  float* xagu    = (float*)take((size_t)NRP * 32 * 4);
  float* aadb    = (float*)take((size_t)NRP * 16 * 4);
  u16*   abgu    = (u16*)take((size_t)NEXP * 32 * DIM * 2);
  u16*   adb     = (u16*)take((size_t)NEXP * 16 * FFD * 2);
  u16*   xg      = (u16*)take((size_t)NRP * DIM * 2);
  u16*   actb    = (u16*)take((size_t)NRP * FFD * 2);
  u16*   downb   = (u16*)take((size_t)2 * NRP * DIM * 2);
  u16*   wgu_t   = (u16*)take((size_t)NEXP * 2 * FFD * DIM * 2);
  u16*   wd_t    = (u16*)take((size_t)NEXP * DIM * FFD * 2);
  (void)ws_size; (void)in_sizes; (void)n_in; (void)out_size;

  // weight transposes (fp32 [K][N] -> bf16 [N][K]) — independent of routing
  transpose_k<<<dim3(128, 32, NEXP), dim3(32, 8), 0, stream>>>(gate_up_w, wgu_t, DIM, 2 * FFD);
  transpose_k<<<dim3(32, 64, NEXP), dim3(32, 8), 0, stream>>>(down_w, wd_t, FFD, DIM);
  cvtA_k<<<256, 256, 0, stream>>>(A_gate, A_up, A_down, abgu, adb);

  router_k<<<T_TOK, 64, 0, stream>>>(x, gate_w, out_logits, sel, selw);
  scan_k<<<1, 1024, 0, stream>>>(sel, pos, offs, rowtok, pairrow);
  gather_k<<<NRP, 256, 0, stream>>>(x, rowtok, xg);
  xa_k<<<NRP / 2, 64, 0, stream>>>(xg, abgu, offs, xagu);
  gemm1_k<<<dim3(16, NTILES), 256, 0, stream>>>(xg, wgu_t, gate_up_b, B_gate, B_up,
                                                xagu, offs, actb);
  aad_k<<<NRP / 2, 64, 0, stream>>>(actb, adb, offs, aadb);
  gemm2_k<<<dim3(4, NTILES, 2), 256, 0, stream>>>(actb, wd_t, down_b, B_down, aadb,
                                                  offs, downb);
  combine_k<<<T_TOK, 256, 0, stream>>>(downb, pairrow, selw, out_final);
}

// Round 10
// 272.088 us; speedup vs baseline: 1.1677x; 1.1677x over previous
//
#include <hip/hip_runtime.h>

#define T_TOK 4096
#define DIM   1024
#define FFD   2048
#define NEXP  4
#define NRP   8704      // 68*128 padded row capacity
#define MTILES 68

typedef unsigned short u16;
typedef __attribute__((ext_vector_type(8))) short short8;
typedef __attribute__((ext_vector_type(4))) float f32x4;
typedef __attribute__((ext_vector_type(8))) unsigned short u16x8;
typedef __attribute__((ext_vector_type(4))) unsigned short u16x4;

typedef __attribute__((address_space(1))) unsigned int as1_u32;
typedef __attribute__((address_space(3))) unsigned int as3_u32;

__device__ __forceinline__ u16 f2bf(float f) {
  union { float f; unsigned u; } v; v.f = f;
  unsigned u = v.u;
  return (u16)((u + 0x7fffu + ((u >> 16) & 1u)) >> 16);   // RNE
}
__device__ __forceinline__ float bf2f(u16 h) {
  union { unsigned u; float f; } v; v.u = ((unsigned)h) << 16;
  return v.f;
}
__device__ __forceinline__ void gload16(const void* g, void* l) {
  __builtin_amdgcn_global_load_lds((const as1_u32*)g, (as3_u32*)l, 16, 0, 0);
}

// ---------------- router: fp32 logits, softmax top-2, renorm ----------------
__global__ void router_k(const float* __restrict__ x, const float* __restrict__ gw,
                         float* __restrict__ logits_out, int* __restrict__ sel,
                         float* __restrict__ selw) {
  int t = blockIdx.x;
  int lane = threadIdx.x;           // block = 64 (one wave)
  float xv[16];
#pragma unroll
  for (int i = 0; i < 16; ++i) xv[i] = x[(size_t)t * DIM + lane + i * 64];
  float l[4];
#pragma unroll
  for (int e = 0; e < 4; ++e) {
    float s = 0.f;
#pragma unroll
    for (int i = 0; i < 16; ++i) s += xv[i] * gw[e * DIM + lane + i * 64];
#pragma unroll
    for (int off = 32; off > 0; off >>= 1) s += __shfl_xor(s, off, 64);
    l[e] = s;
  }
  if (lane == 0) {
#pragma unroll
    for (int e = 0; e < 4; ++e) logits_out[(size_t)t * 4 + e] = l[e];
    int e0 = 0; float b0 = l[0];
    for (int e = 1; e < 4; ++e) if (l[e] > b0) { b0 = l[e]; e0 = e; }
    int e1 = -1; float b1 = -3.4e38f;
    for (int e = 0; e < 4; ++e) if (e != e0 && l[e] > b1) { b1 = l[e]; e1 = e; }
    float p1 = expf(b1 - b0);
    float w0 = 1.f / (1.f + p1);
    sel[2 * t] = e0; sel[2 * t + 1] = e1;
    selw[2 * t] = w0; selw[2 * t + 1] = 1.f - w0;
  }
}

// ------------- deterministic bucket assignment (single block) ---------------
__global__ void scan_k(const int* __restrict__ sel, int* __restrict__ pos,
                       int* __restrict__ offs, int* __restrict__ rowtok,
                       int* __restrict__ pairrow) {
  __shared__ int base[4];
  __shared__ int wsum[16][4];
  __shared__ int off_s[5];
  int tid = threadIdx.x, lane = tid & 63, wid = tid >> 6;   // 1024 threads = 16 waves
  if (tid < 4) base[tid] = 0;
  __syncthreads();
  for (int chunk = 0; chunk < 4; ++chunk) {
    int t = chunk * 1024 + tid;
    int e0 = sel[2 * t], e1 = sel[2 * t + 1];
    unsigned long long ltm = (1ull << lane) - 1ull;
    bool f[4]; int within[4];
#pragma unroll
    for (int e = 0; e < 4; ++e) {
      f[e] = (e0 == e) || (e1 == e);
      unsigned long long m = __ballot(f[e]);
      within[e] = __popcll(m & ltm);
      if (lane == 0) wsum[wid][e] = __popcll(m);
    }
    __syncthreads();
    int wbase[4] = {0, 0, 0, 0}, tot[4] = {0, 0, 0, 0};
    for (int i = 0; i < 16; ++i)
#pragma unroll
      for (int e = 0; e < 4; ++e) {
        int v = wsum[i][e];
        if (i < wid) wbase[e] += v;
        tot[e] += v;
      }
#pragma unroll
    for (int e = 0; e < 4; ++e)
      if (f[e]) {
        int p = base[e] + wbase[e] + within[e];
        if (e0 == e) pos[2 * t] = p; else pos[2 * t + 1] = p;
      }
    __syncthreads();
    if (tid < 4) base[tid] += tot[tid];
    __syncthreads();
  }
  if (tid == 0) {
    int o = 0;
    for (int e = 0; e < 4; ++e) { off_s[e] = o; o += ((base[e] + 127) >> 7) << 7; }
    off_s[4] = o;
    for (int i = 0; i < 5; ++i) offs[i] = off_s[i];
  }
  __syncthreads();
  for (int r = tid; r < NRP; r += 1024) rowtok[r] = -1;
  __syncthreads();
  for (int t = tid; t < T_TOK; t += 1024) {
#pragma unroll
    for (int s = 0; s < 2; ++s) {
      int e = sel[2 * t + s];
      int rr = off_s[e] + pos[2 * t + s];
      pairrow[2 * t + s] = rr;
      rowtok[rr] = t;
    }
  }
}

// ---------------- gather x rows (bucket order) -> bf16 ----------------------
__global__ void gather_k(const float* __restrict__ x, const int* __restrict__ rowtok,
                         u16* __restrict__ xg) {
  int r = blockIdx.x, tid = threadIdx.x;   // 256 threads, 4 floats each
  int t = rowtok[r];
  float4 v = make_float4(0.f, 0.f, 0.f, 0.f);
  if (t >= 0) v = ((const float4*)(x + (size_t)t * DIM))[tid];
  u16x4 o;
  o[0] = f2bf(v.x); o[1] = f2bf(v.y); o[2] = f2bf(v.z); o[3] = f2bf(v.w);
  ((u16x4*)(xg + (size_t)r * DIM))[tid] = o;
}

// -------- pre-convert LoRA A matrices to bf16 (abgu[4][32][1024], adb[4][16][2048])
__global__ void cvtA_k(const float* __restrict__ Ag, const float* __restrict__ Au,
                       const float* __restrict__ Ad, u16* __restrict__ abgu,
                       u16* __restrict__ adb) {
  int g = blockIdx.x * 256 + threadIdx.x;   // each handles 4 elements
  if (g < 32768) {
    int flat = g * 4;
    int e = flat >> 15;
    int rem = flat & 32767;
    int q = rem >> 10;
    int d = rem & 1023;
    const float* src = (q < 16) ? (Ag + ((size_t)e * 16 + q) * DIM + d)
                                : (Au + ((size_t)e * 16 + (q - 16)) * DIM + d);
    float4 v = *(const float4*)src;
    u16x4 o; o[0] = f2bf(v.x); o[1] = f2bf(v.y); o[2] = f2bf(v.z); o[3] = f2bf(v.w);
    *(u16x4*)(abgu + (size_t)flat) = o;
  } else {
    int flat = (g - 32768) * 4;
    float4 v = *(const float4*)(Ad + flat);
    u16x4 o; o[0] = f2bf(v.x); o[1] = f2bf(v.y); o[2] = f2bf(v.z); o[3] = f2bf(v.w);
    *(u16x4*)(adb + (size_t)flat) = o;
  }
}

// ---------------- per-row LoRA A-projections, 2 rows per wave ----------------
__global__ void xa_k(const u16* __restrict__ xg, const u16* __restrict__ abgu,
                     const int* __restrict__ offs, float* __restrict__ xagu) {
  int r0 = blockIdx.x * 2, lane = threadIdx.x;   // block = 64
  int e = 0;
  if (r0 >= offs[1]) e = 1;
  if (r0 >= offs[2]) e = 2;
  if (r0 >= offs[3]) e = 3;
  float x0[16], x1[16];
#pragma unroll
  for (int i = 0; i < 4; ++i) {
    u16x4 v0 = ((const u16x4*)(xg + (size_t)r0 * DIM))[lane + i * 64];
    u16x4 v1 = ((const u16x4*)(xg + (size_t)(r0 + 1) * DIM))[lane + i * 64];
#pragma unroll
    for (int j = 0; j < 4; ++j) { x0[i * 4 + j] = bf2f(v0[j]); x1[i * 4 + j] = bf2f(v1[j]); }
  }
  const u16* A = abgu + (size_t)e * 32 * DIM;
  for (int q = 0; q < 32; ++q) {
    float s0 = 0.f, s1 = 0.f;
#pragma unroll
    for (int i = 0; i < 4; ++i) {
      u16x4 av = ((const u16x4*)(A + (size_t)q * DIM))[lane + i * 64];
#pragma unroll
      for (int j = 0; j < 4; ++j) {
        float a = bf2f(av[j]);
        s0 += x0[i * 4 + j] * a; s1 += x1[i * 4 + j] * a;
      }
    }
#pragma unroll
    for (int off = 32; off > 0; off >>= 1) { s0 += __shfl_xor(s0, off, 64); s1 += __shfl_xor(s1, off, 64); }
    if (lane == 0) { xagu[(size_t)r0 * 32 + q] = s0; xagu[(size_t)(r0 + 1) * 32 + q] = s1; }
  }
}

__global__ void aad_k(const u16* __restrict__ act, const u16* __restrict__ adb,
                      const int* __restrict__ offs, float* __restrict__ aad) {
  int r0 = blockIdx.x * 2, lane = threadIdx.x;
  int e = 0;
  if (r0 >= offs[1]) e = 1;
  if (r0 >= offs[2]) e = 2;
  if (r0 >= offs[3]) e = 3;
  float x0[32], x1[32];
#pragma unroll
  for (int i = 0; i < 8; ++i) {
    u16x4 v0 = ((const u16x4*)(act + (size_t)r0 * FFD))[lane + i * 64];
    u16x4 v1 = ((const u16x4*)(act + (size_t)(r0 + 1) * FFD))[lane + i * 64];
#pragma unroll
    for (int j = 0; j < 4; ++j) { x0[i * 4 + j] = bf2f(v0[j]); x1[i * 4 + j] = bf2f(v1[j]); }
  }
  const u16* A = adb + (size_t)e * 16 * FFD;
  for (int q = 0; q < 16; ++q) {
    float s0 = 0.f, s1 = 0.f;
#pragma unroll
    for (int i = 0; i < 8; ++i) {
      u16x4 av = ((const u16x4*)(A + (size_t)q * FFD))[lane + i * 64];
#pragma unroll
      for (int j = 0; j < 4; ++j) {
        float a = bf2f(av[j]);
        s0 += x0[i * 4 + j] * a; s1 += x1[i * 4 + j] * a;
      }
    }
#pragma unroll
    for (int off = 32; off > 0; off >>= 1) { s0 += __shfl_xor(s0, off, 64); s1 += __shfl_xor(s1, off, 64); }
    if (lane == 0) { aad[(size_t)r0 * 16 + q] = s0; aad[(size_t)(r0 + 1) * 16 + q] = s1; }
  }
}

// ---------------- weight transpose fp32[K][N] -> bf16[N][K] ------------------
__global__ void transpose_k(const float* __restrict__ in, u16* __restrict__ out,
                            int K, int N) {
  int e = blockIdx.z;
  int n0 = blockIdx.x * 32, k0 = blockIdx.y * 32;
  const float* I = in + (size_t)e * K * N;
  u16* O = out + (size_t)e * N * K;
  __shared__ u16 tile[32][33];
#pragma unroll
  for (int i = 0; i < 4; ++i) {
    int k = k0 + threadIdx.y + i * 8;
    tile[threadIdx.y + i * 8][threadIdx.x] = f2bf(I[(size_t)k * N + n0 + threadIdx.x]);
  }
  __syncthreads();
#pragma unroll
  for (int i = 0; i < 4; ++i) {
    int n = n0 + threadIdx.y + i * 8;
    O[(size_t)n * K + k0 + threadIdx.x] = tile[threadIdx.x][threadIdx.y + i * 8];
  }
}

// ---------------- GEMM1: act = swiglu(x@Wgu + b + lora) ---------------------
// Round-6 geometry (128x256, 4 waves 2x2, 3 staging bufs, 72KB, 2 blocks/CU)
// with template-faithful 2-phase pipeline: every ds_read group issued ONE
// PHASE AHEAD, pre-barrier; counted lgkm after the barrier; staging after the
// validating barrier; vmcnt(0) covers the batch issued a full step earlier.
__global__ __launch_bounds__(256, 2) void gemm1_k(
    const u16* __restrict__ xg, const u16* __restrict__ wgu_t,
    const float* __restrict__ gub, const float* __restrict__ Bg,
    const float* __restrict__ Bu, const float* __restrict__ xagu,
    const int* __restrict__ offs, u16* __restrict__ act) {
  __shared__ __align__(16) u16 sAB[36864];   // 3 bufs x (A[128][32] + B[256][32])
  int tid = threadIdx.x, w = tid >> 6, lane = tid & 63;
  int f0 = blockIdx.x * 128;
  int row0 = blockIdx.y * 128;
  int e = 0;
  if (row0 >= offs[1]) e = 1;
  if (row0 >= offs[2]) e = 2;
  if (row0 >= offs[3]) e = 3;
  int wm = w >> 1, wn = w & 1;

  int srow = lane >> 2;
  int scol = ((lane & 3) ^ ((lane >> 3) & 3)) * 8;     // pre-swizzled global src (T2)
  const u16* gA = xg + (size_t)(row0 + w * 32 + srow) * DIM + scol;
  int bhalf = (w < 2) ? (f0 + w * 64) : (2048 + f0 + (w - 2) * 64);
  const u16* gB = wgu_t + ((size_t)e << 22) + (size_t)(bhalf + srow) * DIM + scol;
  int fo = (((lane >> 4) ^ ((lane >> 1) & 3))) * 8;    // swizzled fragment k-offset
  int arb = (wm * 64 + (lane & 15)) * 32 + fo;
  int brb = 4096 + (wn * 128 + (lane & 15)) * 32 + fo;

  f32x4 acc[4][8];
#pragma unroll
  for (int i = 0; i < 4; ++i)
#pragma unroll
    for (int j = 0; j < 8; ++j) acc[i][j] = f32x4{0.f, 0.f, 0.f, 0.f};

  // prologue: batches 0,1 -> bufs 0,1
#pragma unroll
  for (int p = 0; p < 2; ++p) {
    u16* dA = sAB + p * 12288 + w * 1024;
    gload16(gA + p * 32, dA); gload16(gA + 16 * DIM + p * 32, dA + 512);
    u16* dB = sAB + p * 12288 + 4096 + w * 2048;
    gload16(gB + p * 32, dB); gload16(gB + 16 * DIM + p * 32, dB + 512);
    gload16(gB + 32 * DIM + p * 32, dB + 1024); gload16(gB + 48 * DIM + p * 32, dB + 1536);
  }
  asm volatile("s_waitcnt vmcnt(6)" ::: "memory");   // batch 0 landed
  __builtin_amdgcn_s_barrier();                      // validates buf 0
  short8 aC[4], bL[4], bH[4], aN[4], bN[4];
#pragma unroll
  for (int fr = 0; fr < 4; ++fr) aC[fr] = *(const short8*)&sAB[arb + fr * 512];
#pragma unroll
  for (int ni = 0; ni < 4; ++ni) bL[ni] = *(const short8*)&sAB[brb + ni * 512];

#pragma unroll
  for (int t = 0; t < 32; ++t) {
    const u16* cb  = sAB + (t % 3) * 12288;
    const u16* cbn = sAB + ((t + 1) % 3) * 12288;
    // ---- P1: issue b_hi(t) pre-barrier ----
#pragma unroll
    for (int ni = 0; ni < 4; ++ni) bH[ni] = *(const short8*)&cb[brb + (ni + 4) * 512];
    asm volatile("s_waitcnt vmcnt(0)" ::: "memory");   // batch t+1 landed (issued a step ago)
    __builtin_amdgcn_s_barrier();                      // validates buf t+1
    if (t < 30) {                                      // stage batch t+2 (after validating barrier)
      int kk = (t + 2) * 32;
      int bo = ((t + 2) % 3) * 12288;
      u16* dA = sAB + bo + w * 1024;
      gload16(gA + kk, dA); gload16(gA + 16 * DIM + kk, dA + 512);
      u16* dB = sAB + bo + 4096 + w * 2048;
      gload16(gB + kk, dB); gload16(gB + 16 * DIM + kk, dB + 512);
      gload16(gB + 32 * DIM + kk, dB + 1024); gload16(gB + 48 * DIM + kk, dB + 1536);
    }
    asm volatile("s_waitcnt lgkmcnt(4)" ::: "memory"); // aC,bL done; 4 = bH outstanding
    __builtin_amdgcn_sched_barrier(0);
    __builtin_amdgcn_s_setprio(1);
#pragma unroll
    for (int mi = 0; mi < 4; ++mi)
#pragma unroll
      for (int ni = 0; ni < 4; ++ni)
        acc[mi][ni] = __builtin_amdgcn_mfma_f32_16x16x32_bf16(aC[mi], bL[ni], acc[mi][ni], 0, 0, 0);
    __builtin_amdgcn_s_setprio(0);
    // ---- P2: issue a,b_lo(t+1) pre-barrier (buf t+1 validated at B1) ----
    if (t < 31) {
#pragma unroll
      for (int fr = 0; fr < 4; ++fr) aN[fr] = *(const short8*)&cbn[arb + fr * 512];
#pragma unroll
      for (int ni = 0; ni < 4; ++ni) bN[ni] = *(const short8*)&cbn[brb + ni * 512];
    }
    __builtin_amdgcn_s_barrier();
    if (t < 31) asm volatile("s_waitcnt lgkmcnt(8)" ::: "memory");  // bH done; 8 = next a/b
    else        asm volatile("s_waitcnt lgkmcnt(0)" ::: "memory");
    __builtin_amdgcn_sched_barrier(0);
    __builtin_amdgcn_s_setprio(1);
#pragma unroll
    for (int mi = 0; mi < 4; ++mi)
#pragma unroll
      for (int ni = 0; ni < 4; ++ni)
        acc[mi][ni + 4] = __builtin_amdgcn_mfma_f32_16x16x32_bf16(aC[mi], bH[ni], acc[mi][ni + 4], 0, 0, 0);
    __builtin_amdgcn_s_setprio(0);
    if (t < 31) {
#pragma unroll
      for (int fr = 0; fr < 4; ++fr) aC[fr] = aN[fr];
#pragma unroll
      for (int ni = 0; ni < 4; ++ni) bL[ni] = bN[ni];
    }
  }

  // ---- LoRA + bias as one extra K=32 MFMA step ----
  __syncthreads();
  {
    int rl = tid & 127, half = tid >> 7;
    int sw = (rl >> 1) & 3;
    int abase = half * 12288 + rl * 32;
    u16 tmp[16];
#pragma unroll
    for (int q = 0; q < 16; ++q) tmp[q] = f2bf(2.f * xagu[(size_t)(row0 + rl) * 32 + half * 16 + q]);
    *(u16x8*)&sAB[abase + (0 ^ sw) * 8] = *(u16x8*)&tmp[0];
    *(u16x8*)&sAB[abase + (1 ^ sw) * 8] = *(u16x8*)&tmp[8];
    u16 t2[8] = {0x3f80, 0, 0, 0, 0, 0, 0, 0};
    u16 t3[8] = {0, 0, 0, 0, 0, 0, 0, 0};
    *(u16x8*)&sAB[abase + (2 ^ sw) * 8] = *(u16x8*)&t2[0];
    *(u16x8*)&sAB[abase + (3 ^ sw) * 8] = *(u16x8*)&t3[0];
    // B-lora: one row per thread
    int r = tid, fb = r & 127, bh = r >> 7;
    int swb = (r >> 1) & 3;
    int bbase = 4096 + r * 32;
    const float* Bsrc = bh ? Bu : Bg;
    float bias = gub[e * 4096 + (bh ? (2048 + f0 + fb) : (f0 + fb))];
    u16 tb[16];
#pragma unroll
    for (int q = 0; q < 16; ++q) tb[q] = f2bf(Bsrc[((size_t)e * FFD + f0 + fb) * 16 + q]);
    *(u16x8*)&sAB[bbase + (0 ^ swb) * 8] = *(u16x8*)&tb[0];
    *(u16x8*)&sAB[bbase + (1 ^ swb) * 8] = *(u16x8*)&tb[8];
    u16 t2b[8] = {f2bf(bias), 0, 0, 0, 0, 0, 0, 0};
    *(u16x8*)&sAB[bbase + (2 ^ swb) * 8] = *(u16x8*)&t2b[0];
    *(u16x8*)&sAB[bbase + (3 ^ swb) * 8] = *(u16x8*)&t3[0];
  }
  __syncthreads();
  {
    int aBase = wn ? 12288 : 0;
    short8 a[4], bb[8];
#pragma unroll
    for (int mi = 0; mi < 4; ++mi)
      a[mi] = *(const short8*)&sAB[aBase + arb + mi * 512];
#pragma unroll
    for (int ni = 0; ni < 8; ++ni)
      bb[ni] = *(const short8*)&sAB[brb + ni * 512];
#pragma unroll
    for (int mi = 0; mi < 4; ++mi)
#pragma unroll
      for (int ni = 0; ni < 8; ++ni)
        acc[mi][ni] = __builtin_amdgcn_mfma_f32_16x16x32_bf16(a[mi], bb[ni], acc[mi][ni], 0, 0, 0);
  }
  // ---- SwiGLU via LDS exchange: sOut[128][256] bf16, XOR bank-swizzled ----
  __syncthreads();
#pragma unroll
  for (int mi = 0; mi < 4; ++mi)
#pragma unroll
    for (int ni = 0; ni < 8; ++ni)
#pragma unroll
      for (int j = 0; j < 4; ++j) {
        int row = wm * 64 + mi * 16 + (lane >> 4) * 4 + j;
        int br = wn * 128 + ni * 16 + (lane & 15);
        int key = ((row & 3) ^ ((row >> 2) & 3)) << 4;
        sAB[row * 256 + (br ^ key)] = f2bf(acc[mi][ni][j]);
      }
  __syncthreads();
  {
    int fc = (tid & 15) * 8;
    int rb = tid >> 4;
#pragma unroll
    for (int it = 0; it < 8; ++it) {
      int row = rb + it * 16;
      int key = ((row & 3) ^ ((row >> 2) & 3)) << 4;
      u16x8 gv = *(const u16x8*)&sAB[row * 256 + (fc ^ key)];
      u16x8 uv = *(const u16x8*)&sAB[row * 256 + ((fc + 128) ^ key)];
      u16x8 ov;
#pragma unroll
      for (int j = 0; j < 8; ++j) {
        float g = bf2f(gv[j]);
        float u = bf2f(uv[j]);
        float s = g / (1.f + __expf(-g));
        ov[j] = f2bf(s * u);
      }
      *(u16x8*)(act + (size_t)(row0 + row) * FFD + f0 + fc) = ov;
    }
  }
}

// ------- GEMM2: down = act@Wd + b + lora; 128x256 tile, split-K=2 -----------
__global__ __launch_bounds__(256, 2) void gemm2_k(
    const u16* __restrict__ act, const u16* __restrict__ wd_t,
    const float* __restrict__ db, const float* __restrict__ Bd,
    const float* __restrict__ aad, const int* __restrict__ offs,
    u16* __restrict__ down) {
  __shared__ __align__(16) u16 sAB[36864];
  int tid = threadIdx.x, w = tid >> 6, lane = tid & 63;
  int n0 = blockIdx.x * 256;
  int row0 = blockIdx.y * 128;
  int ks = blockIdx.z;
  size_t kbase = (size_t)ks * 1024;
  int e = 0;
  if (row0 >= offs[1]) e = 1;
  if (row0 >= offs[2]) e = 2;
  if (row0 >= offs[3]) e = 3;
  int wm = w >> 1, wn = w & 1;

  int srow = lane >> 2;
  int scol = ((lane & 3) ^ ((lane >> 3) & 3)) * 8;
  const u16* gA = act + (size_t)(row0 + w * 32 + srow) * FFD + kbase + scol;
  const u16* gB = wd_t + (size_t)e * DIM * FFD + (size_t)(n0 + w * 64 + srow) * FFD + kbase + scol;
  int fo = (((lane >> 4) ^ ((lane >> 1) & 3))) * 8;
  int arb = (wm * 64 + (lane & 15)) * 32 + fo;
  int brb = 4096 + (wn * 128 + (lane & 15)) * 32 + fo;

  f32x4 acc[4][8];
#pragma unroll
  for (int i = 0; i < 4; ++i)
#pragma unroll
    for (int j = 0; j < 8; ++j) acc[i][j] = f32x4{0.f, 0.f, 0.f, 0.f};

#pragma unroll
  for (int p = 0; p < 2; ++p) {
    u16* dA = sAB + p * 12288 + w * 1024;
    gload16(gA + p * 32, dA); gload16(gA + 16 * FFD + p * 32, dA + 512);
    u16* dB = sAB + p * 12288 + 4096 + w * 2048;
    gload16(gB + p * 32, dB); gload16(gB + 16 * FFD + p * 32, dB + 512);
    gload16(gB + 32 * FFD + p * 32, dB + 1024); gload16(gB + 48 * FFD + p * 32, dB + 1536);
  }
  asm volatile("s_waitcnt vmcnt(6)" ::: "memory");
  __builtin_amdgcn_s_barrier();
  short8 aC[4], bL[4], bH[4], aN[4], bN[4];
#pragma unroll
  for (int fr = 0; fr < 4; ++fr) aC[fr] = *(const short8*)&sAB[arb + fr * 512];
#pragma unroll
  for (int ni = 0; ni < 4; ++ni) bL[ni] = *(const short8*)&sAB[brb + ni * 512];

#pragma unroll
  for (int t = 0; t < 32; ++t) {
    const u16* cb  = sAB + (t % 3) * 12288;
    const u16* cbn = sAB + ((t + 1) % 3) * 12288;
#pragma unroll
    for (int ni = 0; ni < 4; ++ni) bH[ni] = *(const short8*)&cb[brb + (ni + 4) * 512];
    asm volatile("s_waitcnt vmcnt(0)" ::: "memory");
    __builtin_amdgcn_s_barrier();
    if (t < 30) {
      int kk = (t + 2) * 32;
      int bo = ((t + 2) % 3) * 12288;
      u16* dA = sAB + bo + w * 1024;
      gload16(gA + kk, dA); gload16(gA + 16 * FFD + kk, dA + 512);
      u16* dB = sAB + bo + 4096 + w * 2048;
      gload16(gB + kk, dB); gload16(gB + 16 * FFD + kk, dB + 512);
      gload16(gB + 32 * FFD + kk, dB + 1024); gload16(gB + 48 * FFD + kk, dB + 1536);
    }
    asm volatile("s_waitcnt lgkmcnt(4)" ::: "memory");
    __builtin_amdgcn_sched_barrier(0);
    __builtin_amdgcn_s_setprio(1);
#pragma unroll
    for (int mi = 0; mi < 4; ++mi)
#pragma unroll
      for (int ni = 0; ni < 4; ++ni)
        acc[mi][ni] = __builtin_amdgcn_mfma_f32_16x16x32_bf16(aC[mi], bL[ni], acc[mi][ni], 0, 0, 0);
    __builtin_amdgcn_s_setprio(0);
    if (t < 31) {
#pragma unroll
      for (int fr = 0; fr < 4; ++fr) aN[fr] = *(const short8*)&cbn[arb + fr * 512];
#pragma unroll
      for (int ni = 0; ni < 4; ++ni) bN[ni] = *(const short8*)&cbn[brb + ni * 512];
    }
    __builtin_amdgcn_s_barrier();
    if (t < 31) asm volatile("s_waitcnt lgkmcnt(8)" ::: "memory");
    else        asm volatile("s_waitcnt lgkmcnt(0)" ::: "memory");
    __builtin_amdgcn_sched_barrier(0);
    __builtin_amdgcn_s_setprio(1);
#pragma unroll
    for (int mi = 0; mi < 4; ++mi)
#pragma unroll
      for (int ni = 0; ni < 4; ++ni)
        acc[mi][ni + 4] = __builtin_amdgcn_mfma_f32_16x16x32_bf16(aC[mi], bH[ni], acc[mi][ni + 4], 0, 0, 0);
    __builtin_amdgcn_s_setprio(0);
    if (t < 31) {
#pragma unroll
      for (int fr = 0; fr < 4; ++fr) aC[fr] = aN[fr];
#pragma unroll
      for (int ni = 0; ni < 4; ++ni) bL[ni] = bN[ni];
    }
  }

  if (ks == 0) {
    // ---- LoRA-down + bias as one extra K=32 MFMA step ----
    __syncthreads();
    {
      int r = tid >> 1, kh = tid & 1;
      int sw = (r >> 1) & 3;
      int o0 = r * 32 + ((2 * kh + 0) ^ sw) * 8;
      int o1 = r * 32 + ((2 * kh + 1) ^ sw) * 8;
      u16 tmp[16];
      if (kh == 0) {
#pragma unroll
        for (int q = 0; q < 16; ++q) tmp[q] = f2bf(2.f * aad[(size_t)(row0 + r) * 16 + q]);
      } else {
#pragma unroll
        for (int q = 0; q < 16; ++q) tmp[q] = 0;
        tmp[0] = 0x3f80;
      }
      *(u16x8*)&sAB[o0] = *(u16x8*)&tmp[0];
      *(u16x8*)&sAB[o1] = *(u16x8*)&tmp[8];
      // B-lora: one row per thread (256 rows)
      int r2 = tid;
      int swb = (r2 >> 1) & 3;
      int bbase = 4096 + r2 * 32;
      u16 tb[16];
#pragma unroll
      for (int q = 0; q < 16; ++q) tb[q] = f2bf(Bd[((size_t)e * DIM + n0 + r2) * 16 + q]);
      *(u16x8*)&sAB[bbase + (0 ^ swb) * 8] = *(u16x8*)&tb[0];
      *(u16x8*)&sAB[bbase + (1 ^ swb) * 8] = *(u16x8*)&tb[8];
      u16 t2b[8] = {f2bf(db[e * DIM + n0 + r2]), 0, 0, 0, 0, 0, 0, 0};
      u16 t3b[8] = {0, 0, 0, 0, 0, 0, 0, 0};
      *(u16x8*)&sAB[bbase + (2 ^ swb) * 8] = *(u16x8*)&t2b[0];
      *(u16x8*)&sAB[bbase + (3 ^ swb) * 8] = *(u16x8*)&t3b[0];
    }
    __syncthreads();
    {
      short8 a[4], bb[8];
#pragma unroll
      for (int mi = 0; mi < 4; ++mi)
        a[mi] = *(const short8*)&sAB[arb + mi * 512];
#pragma unroll
      for (int ni = 0; ni < 8; ++ni)
        bb[ni] = *(const short8*)&sAB[brb + ni * 512];
#pragma unroll
      for (int mi = 0; mi < 4; ++mi)
#pragma unroll
        for (int ni = 0; ni < 8; ++ni)
          acc[mi][ni] = __builtin_amdgcn_mfma_f32_16x16x32_bf16(a[mi], bb[ni], acc[mi][ni], 0, 0, 0);
    }
  }
  // ---- store bf16 partial ----
#pragma unroll
  for (int mi = 0; mi < 4; ++mi)
#pragma unroll
    for (int ni = 0; ni < 8; ++ni)
#pragma unroll
      for (int j = 0; j < 4; ++j) {
        int lr = wm * 64 + mi * 16 + (lane >> 4) * 4 + j;
        int lc = wn * 128 + ni * 16 + (lane & 15);
        down[((size_t)ks * NRP + row0 + lr) * DIM + n0 + lc] = f2bf(acc[mi][ni][j]);
      }
}

// ---------------- weighted combine (sums split-K halves) --------------------
__global__ void combine_k(const u16* __restrict__ down, const int* __restrict__ pairrow,
                          const float* __restrict__ selw, float* __restrict__ out) {
  int t = blockIdx.x, tid = threadIdx.x;   // 256 threads, 4 cols each
  int r0 = pairrow[2 * t], r1 = pairrow[2 * t + 1];
  float w0 = selw[2 * t], w1 = selw[2 * t + 1];
  u16x4 a0 = *(const u16x4*)(down + ((size_t)r0) * DIM + tid * 4);
  u16x4 a1 = *(const u16x4*)(down + ((size_t)NRP + r0) * DIM + tid * 4);
  u16x4 b0 = *(const u16x4*)(down + ((size_t)r1) * DIM + tid * 4);
  u16x4 b1 = *(const u16x4*)(down + ((size_t)NRP + r1) * DIM + tid * 4);
  f32x4 o;
#pragma unroll
  for (int j = 0; j < 4; ++j)
    o[j] = w0 * (bf2f(a0[j]) + bf2f(a1[j])) + w1 * (bf2f(b0[j]) + bf2f(b1[j]));
  *(f32x4*)(out + (size_t)t * DIM + tid * 4) = o;
}

extern "C" void kernel_launch(void* const* d_in, const int* in_sizes, int n_in,
                              void* d_out, int out_size, void* d_ws, size_t ws_size,
                              hipStream_t stream) {
  const float* x         = (const float*)d_in[0];
  const float* gate_w    = (const float*)d_in[1];
  const float* gate_up_w = (const float*)d_in[2];
  const float* gate_up_b = (const float*)d_in[3];
  const float* down_w    = (const float*)d_in[4];
  const float* down_b    = (const float*)d_in[5];
  const float* A_gate    = (const float*)d_in[6];
  const float* B_gate    = (const float*)d_in[7];
  const float* A_up      = (const float*)d_in[8];
  const float* B_up      = (const float*)d_in[9];
  const float* A_down    = (const float*)d_in[10];
  const float* B_down    = (const float*)d_in[11];

  float* out_final  = (float*)d_out;
  float* out_logits = out_final + (size_t)T_TOK * DIM;

  char* ws = (char*)d_ws;
  size_t o = 0;
  auto take = [&](size_t bytes) -> void* {
    void* p = ws + o;
    o = (o + bytes + 255) & ~(size_t)255;
    return p;
  };
  int*   offs    = (int*)take(64);
  int*   sel     = (int*)take((size_t)T_TOK * 2 * 4);
  float* selw    = (float*)take((size_t)T_TOK * 2 * 4);
  int*   pos     = (int*)take((size_t)T_TOK * 2 * 4);
  int*   pairrow = (int*)take((size_t)T_TOK * 2 * 4);
  int*   rowtok  = (int*)take((size_t)NRP * 4);
  float* xagu    = (float*)take((size_t)NRP * 32 * 4);
  float* aadb    = (float*)take((size_t)NRP * 16 * 4);
  u16*   abgu    = (u16*)take((size_t)NEXP * 32 * DIM * 2);
  u16*   adb     = (u16*)take((size_t)NEXP * 16 * FFD * 2);
  u16*   xg      = (u16*)take((size_t)NRP * DIM * 2);
  u16*   actb    = (u16*)take((size_t)NRP * FFD * 2);
  u16*   downb   = (u16*)take((size_t)2 * NRP * DIM * 2);
  u16*   wgu_t   = (u16*)take((size_t)NEXP * 2 * FFD * DIM * 2);
  u16*   wd_t    = (u16*)take((size_t)NEXP * DIM * FFD * 2);
  (void)ws_size; (void)in_sizes; (void)n_in; (void)out_size;

  // weight transposes (fp32 [K][N] -> bf16 [N][K]) — independent of routing
  transpose_k<<<dim3(128, 32, NEXP), dim3(32, 8), 0, stream>>>(gate_up_w, wgu_t, DIM, 2 * FFD);
  transpose_k<<<dim3(32, 64, NEXP), dim3(32, 8), 0, stream>>>(down_w, wd_t, FFD, DIM);
  cvtA_k<<<256, 256, 0, stream>>>(A_gate, A_up, A_down, abgu, adb);

  router_k<<<T_TOK, 64, 0, stream>>>(x, gate_w, out_logits, sel, selw);
  scan_k<<<1, 1024, 0, stream>>>(sel, pos, offs, rowtok, pairrow);
  gather_k<<<NRP, 256, 0, stream>>>(x, rowtok, xg);
  xa_k<<<NRP / 2, 64, 0, stream>>>(xg, abgu, offs, xagu);
  gemm1_k<<<dim3(16, MTILES), 256, 0, stream>>>(xg, wgu_t, gate_up_b, B_gate, B_up,
                                                xagu, offs, actb);
  aad_k<<<NRP / 2, 64, 0, stream>>>(actb, adb, offs, aadb);
  gemm2_k<<<dim3(4, MTILES, 2), 256, 0, stream>>>(actb, wd_t, down_b, B_down, aadb, offs, downb);
  combine_k<<<T_TOK, 256, 0, stream>>>(downb, pairrow, selw, out_final);
}

// Round 11
// 254.894 us; speedup vs baseline: 1.2465x; 1.0675x over previous
//
#include <hip/hip_runtime.h>

#define T_TOK 4096
#define DIM   1024
#define FFD   2048
#define NEXP  4
#define NRP   8704      // 68*128 padded row capacity
#define MTILES 68

typedef unsigned short u16;
typedef __attribute__((ext_vector_type(8))) short short8;
typedef __attribute__((ext_vector_type(4))) float f32x4;
typedef __attribute__((ext_vector_type(8))) unsigned short u16x8;
typedef __attribute__((ext_vector_type(4))) unsigned short u16x4;

typedef __attribute__((address_space(1))) unsigned int as1_u32;
typedef __attribute__((address_space(3))) unsigned int as3_u32;

__device__ __forceinline__ u16 f2bf(float f) {
  union { float f; unsigned u; } v; v.f = f;
  unsigned u = v.u;
  return (u16)((u + 0x7fffu + ((u >> 16) & 1u)) >> 16);   // RNE
}
__device__ __forceinline__ float bf2f(u16 h) {
  union { unsigned u; float f; } v; v.u = ((unsigned)h) << 16;
  return v.f;
}
__device__ __forceinline__ void gload16(const void* g, void* l) {
  __builtin_amdgcn_global_load_lds((const as1_u32*)g, (as3_u32*)l, 16, 0, 0);
}

// ---------------- router: fp32 logits, softmax top-2, renorm (float4) -------
__global__ void router_k(const float* __restrict__ x, const float* __restrict__ gw,
                         float* __restrict__ logits_out, int* __restrict__ sel,
                         float* __restrict__ selw) {
  int t = blockIdx.x;
  int lane = threadIdx.x;           // block = 64 (one wave)
  float4 xv[4];
#pragma unroll
  for (int i = 0; i < 4; ++i) xv[i] = ((const float4*)(x + (size_t)t * DIM))[lane + i * 64];
  float l[4];
#pragma unroll
  for (int e = 0; e < 4; ++e) {
    float s = 0.f;
#pragma unroll
    for (int i = 0; i < 4; ++i) {
      float4 g = ((const float4*)(gw + (size_t)e * DIM))[lane + i * 64];
      s += xv[i].x * g.x + xv[i].y * g.y + xv[i].z * g.z + xv[i].w * g.w;
    }
#pragma unroll
    for (int off = 32; off > 0; off >>= 1) s += __shfl_xor(s, off, 64);
    l[e] = s;
  }
  if (lane == 0) {
#pragma unroll
    for (int e = 0; e < 4; ++e) logits_out[(size_t)t * 4 + e] = l[e];
    int e0 = 0; float b0 = l[0];
    for (int e = 1; e < 4; ++e) if (l[e] > b0) { b0 = l[e]; e0 = e; }
    int e1 = -1; float b1 = -3.4e38f;
    for (int e = 0; e < 4; ++e) if (e != e0 && l[e] > b1) { b1 = l[e]; e1 = e; }
    float p1 = expf(b1 - b0);
    float w0 = 1.f / (1.f + p1);
    sel[2 * t] = e0; sel[2 * t + 1] = e1;
    selw[2 * t] = w0; selw[2 * t + 1] = 1.f - w0;
  }
}

// ------------- deterministic bucket assignment (single block) ---------------
__global__ void scan_k(const int* __restrict__ sel, int* __restrict__ pos,
                       int* __restrict__ offs, int* __restrict__ rowtok,
                       int* __restrict__ pairrow) {
  __shared__ int base[4];
  __shared__ int wsum[16][4];
  __shared__ int off_s[5];
  int tid = threadIdx.x, lane = tid & 63, wid = tid >> 6;   // 1024 threads = 16 waves
  if (tid < 4) base[tid] = 0;
  __syncthreads();
  for (int chunk = 0; chunk < 4; ++chunk) {
    int t = chunk * 1024 + tid;
    int e0 = sel[2 * t], e1 = sel[2 * t + 1];
    unsigned long long ltm = (1ull << lane) - 1ull;
    bool f[4]; int within[4];
#pragma unroll
    for (int e = 0; e < 4; ++e) {
      f[e] = (e0 == e) || (e1 == e);
      unsigned long long m = __ballot(f[e]);
      within[e] = __popcll(m & ltm);
      if (lane == 0) wsum[wid][e] = __popcll(m);
    }
    __syncthreads();
    int wbase[4] = {0, 0, 0, 0}, tot[4] = {0, 0, 0, 0};
    for (int i = 0; i < 16; ++i)
#pragma unroll
      for (int e = 0; e < 4; ++e) {
        int v = wsum[i][e];
        if (i < wid) wbase[e] += v;
        tot[e] += v;
      }
#pragma unroll
    for (int e = 0; e < 4; ++e)
      if (f[e]) {
        int p = base[e] + wbase[e] + within[e];
        if (e0 == e) pos[2 * t] = p; else pos[2 * t + 1] = p;
      }
    __syncthreads();
    if (tid < 4) base[tid] += tot[tid];
    __syncthreads();
  }
  if (tid == 0) {
    int o = 0;
    for (int e = 0; e < 4; ++e) { off_s[e] = o; o += ((base[e] + 127) >> 7) << 7; }
    off_s[4] = o;
    for (int i = 0; i < 5; ++i) offs[i] = off_s[i];
  }
  __syncthreads();
  for (int r = tid; r < NRP; r += 1024) rowtok[r] = -1;
  __syncthreads();
  for (int t = tid; t < T_TOK; t += 1024) {
#pragma unroll
    for (int s = 0; s < 2; ++s) {
      int e = sel[2 * t + s];
      int rr = off_s[e] + pos[2 * t + s];
      pairrow[2 * t + s] = rr;
      rowtok[rr] = t;
    }
  }
}

// -------- pre-convert LoRA A matrices to bf16 (abgu[4][32][1024], adb[4][16][2048])
__global__ void cvtA_k(const float* __restrict__ Ag, const float* __restrict__ Au,
                       const float* __restrict__ Ad, u16* __restrict__ abgu,
                       u16* __restrict__ adb) {
  int g = blockIdx.x * 256 + threadIdx.x;   // each handles 4 elements
  if (g < 32768) {
    int flat = g * 4;
    int e = flat >> 15;
    int rem = flat & 32767;
    int q = rem >> 10;
    int d = rem & 1023;
    const float* src = (q < 16) ? (Ag + ((size_t)e * 16 + q) * DIM + d)
                                : (Au + ((size_t)e * 16 + (q - 16)) * DIM + d);
    float4 v = *(const float4*)src;
    u16x4 o; o[0] = f2bf(v.x); o[1] = f2bf(v.y); o[2] = f2bf(v.z); o[3] = f2bf(v.w);
    *(u16x4*)(abgu + (size_t)flat) = o;
  } else {
    int flat = (g - 32768) * 4;
    float4 v = *(const float4*)(Ad + flat);
    u16x4 o; o[0] = f2bf(v.x); o[1] = f2bf(v.y); o[2] = f2bf(v.z); o[3] = f2bf(v.w);
    *(u16x4*)(adb + (size_t)flat) = o;
  }
}

// ------- FUSED gather + LoRA-A projection: x -> xg (bf16) and xagu ----------
// 2 rows per wave; x read once (fp32), converted in-register, written to xg,
// and the 32 LoRA dots computed from the same registers (saves xg re-read).
__global__ void gatherxa_k(const float* __restrict__ x, const int* __restrict__ rowtok,
                           const u16* __restrict__ abgu, const int* __restrict__ offs,
                           u16* __restrict__ xg, float* __restrict__ xagu) {
  int r0 = blockIdx.x * 2, lane = threadIdx.x;   // block = 64
  int e = 0;
  if (r0 >= offs[1]) e = 1;
  if (r0 >= offs[2]) e = 2;
  if (r0 >= offs[3]) e = 3;
  int t0 = rowtok[r0], t1 = rowtok[r0 + 1];
  float x0[16], x1[16];
#pragma unroll
  for (int i = 0; i < 4; ++i) {
    float4 v0 = make_float4(0.f, 0.f, 0.f, 0.f), v1 = v0;
    if (t0 >= 0) v0 = ((const float4*)(x + (size_t)t0 * DIM))[lane + i * 64];
    if (t1 >= 0) v1 = ((const float4*)(x + (size_t)t1 * DIM))[lane + i * 64];
    x0[i * 4 + 0] = v0.x; x0[i * 4 + 1] = v0.y; x0[i * 4 + 2] = v0.z; x0[i * 4 + 3] = v0.w;
    x1[i * 4 + 0] = v1.x; x1[i * 4 + 1] = v1.y; x1[i * 4 + 2] = v1.z; x1[i * 4 + 3] = v1.w;
    u16x4 o0, o1;
#pragma unroll
    for (int j = 0; j < 4; ++j) { o0[j] = f2bf(x0[i * 4 + j]); o1[j] = f2bf(x1[i * 4 + j]); }
    ((u16x4*)(xg + (size_t)r0 * DIM))[lane + i * 64] = o0;
    ((u16x4*)(xg + (size_t)(r0 + 1) * DIM))[lane + i * 64] = o1;
    // keep bf16-rounded values for the dot products (matches previous 2-kernel path)
#pragma unroll
    for (int j = 0; j < 4; ++j) { x0[i * 4 + j] = bf2f(o0[j]); x1[i * 4 + j] = bf2f(o1[j]); }
  }
  const u16* A = abgu + (size_t)e * 32 * DIM;
  for (int q = 0; q < 32; ++q) {
    float s0 = 0.f, s1 = 0.f;
#pragma unroll
    for (int i = 0; i < 4; ++i) {
      u16x4 av = ((const u16x4*)(A + (size_t)q * DIM))[lane + i * 64];
#pragma unroll
      for (int j = 0; j < 4; ++j) {
        float a = bf2f(av[j]);
        s0 += x0[i * 4 + j] * a; s1 += x1[i * 4 + j] * a;
      }
    }
#pragma unroll
    for (int off = 32; off > 0; off >>= 1) { s0 += __shfl_xor(s0, off, 64); s1 += __shfl_xor(s1, off, 64); }
    if (lane == 0) { xagu[(size_t)r0 * 32 + q] = s0; xagu[(size_t)(r0 + 1) * 32 + q] = s1; }
  }
}

__global__ void aad_k(const u16* __restrict__ act, const u16* __restrict__ adb,
                      const int* __restrict__ offs, float* __restrict__ aad) {
  int r0 = blockIdx.x * 2, lane = threadIdx.x;
  int e = 0;
  if (r0 >= offs[1]) e = 1;
  if (r0 >= offs[2]) e = 2;
  if (r0 >= offs[3]) e = 3;
  float x0[32], x1[32];
#pragma unroll
  for (int i = 0; i < 8; ++i) {
    u16x4 v0 = ((const u16x4*)(act + (size_t)r0 * FFD))[lane + i * 64];
    u16x4 v1 = ((const u16x4*)(act + (size_t)(r0 + 1) * FFD))[lane + i * 64];
#pragma unroll
    for (int j = 0; j < 4; ++j) { x0[i * 4 + j] = bf2f(v0[j]); x1[i * 4 + j] = bf2f(v1[j]); }
  }
  const u16* A = adb + (size_t)e * 16 * FFD;
  for (int q = 0; q < 16; ++q) {
    float s0 = 0.f, s1 = 0.f;
#pragma unroll
    for (int i = 0; i < 8; ++i) {
      u16x4 av = ((const u16x4*)(A + (size_t)q * FFD))[lane + i * 64];
#pragma unroll
      for (int j = 0; j < 4; ++j) {
        float a = bf2f(av[j]);
        s0 += x0[i * 4 + j] * a; s1 += x1[i * 4 + j] * a;
      }
    }
#pragma unroll
    for (int off = 32; off > 0; off >>= 1) { s0 += __shfl_xor(s0, off, 64); s1 += __shfl_xor(s1, off, 64); }
    if (lane == 0) { aad[(size_t)r0 * 16 + q] = s0; aad[(size_t)(r0 + 1) * 16 + q] = s1; }
  }
}

// ---------------- weight transpose fp32[K][N] -> bf16[N][K] ------------------
__global__ void transpose_k(const float* __restrict__ in, u16* __restrict__ out,
                            int K, int N) {
  int e = blockIdx.z;
  int n0 = blockIdx.x * 32, k0 = blockIdx.y * 32;
  const float* I = in + (size_t)e * K * N;
  u16* O = out + (size_t)e * N * K;
  __shared__ u16 tile[32][33];
#pragma unroll
  for (int i = 0; i < 4; ++i) {
    int k = k0 + threadIdx.y + i * 8;
    tile[threadIdx.y + i * 8][threadIdx.x] = f2bf(I[(size_t)k * N + n0 + threadIdx.x]);
  }
  __syncthreads();
#pragma unroll
  for (int i = 0; i < 4; ++i) {
    int n = n0 + threadIdx.y + i * 8;
    O[(size_t)n * K + k0 + threadIdx.x] = tile[threadIdx.x][threadIdx.y + i * 8];
  }
}

// ---------------- GEMM1: act = swiglu(x@Wgu + b + lora) ---------------------
// Round-6 best-known: 128x256 tile, 4 waves 2x2, triple-buffered 24KB staging,
// counted vmcnt(6) depth-2 pipeline, full unroll, T2 swizzle. (5 scheduling
// variants benched 96-142us; this one is the 96us floor for this structure.)
__global__ __launch_bounds__(256, 2) void gemm1_k(
    const u16* __restrict__ xg, const u16* __restrict__ wgu_t,
    const float* __restrict__ gub, const float* __restrict__ Bg,
    const float* __restrict__ Bu, const float* __restrict__ xagu,
    const int* __restrict__ offs, u16* __restrict__ act) {
  __shared__ __align__(16) u16 sAB[36864];   // 3 bufs x (A[128][32] + B[256][32]) = 72KB
  int tid = threadIdx.x, w = tid >> 6, lane = tid & 63;
  int f0 = blockIdx.x * 128;
  int row0 = blockIdx.y * 128;
  int e = 0;
  if (row0 >= offs[1]) e = 1;
  if (row0 >= offs[2]) e = 2;
  if (row0 >= offs[3]) e = 3;
  int wm = w >> 1, wn = w & 1;

  int srow = lane >> 2;
  int scol = ((lane & 3) ^ ((lane >> 3) & 3)) * 8;     // pre-swizzled global src (T2)
  const u16* gA = xg + (size_t)(row0 + w * 32 + srow) * DIM + scol;
  int bhalf = (w < 2) ? (f0 + w * 64) : (2048 + f0 + (w - 2) * 64);
  const u16* gB = wgu_t + ((size_t)e << 22) + (size_t)(bhalf + srow) * DIM + scol;
  int fo = (((lane >> 4) ^ ((lane >> 1) & 3))) * 8;    // swizzled fragment k-offset
  int arb = (wm * 64 + (lane & 15)) * 32 + fo;         // A-frag base (rel. to buf)
  int brb = 4096 + (wn * 128 + (lane & 15)) * 32 + fo; // B-frag base (rel. to buf)

  f32x4 acc[4][8];
#pragma unroll
  for (int i = 0; i < 4; ++i)
#pragma unroll
    for (int j = 0; j < 8; ++j) acc[i][j] = f32x4{0.f, 0.f, 0.f, 0.f};

  // prologue: batches 0,1 -> bufs 0,1 (6 gloads per wave per batch)
#pragma unroll
  for (int p = 0; p < 2; ++p) {
    u16* dA = sAB + p * 12288 + w * 1024;
    gload16(gA + p * 32, dA); gload16(gA + 16 * DIM + p * 32, dA + 512);
    u16* dB = sAB + p * 12288 + 4096 + w * 2048;
    gload16(gB + p * 32, dB); gload16(gB + 16 * DIM + p * 32, dB + 512);
    gload16(gB + 32 * DIM + p * 32, dB + 1024); gload16(gB + 48 * DIM + p * 32, dB + 1536);
  }
#pragma unroll
  for (int t = 0; t < 32; ++t) {
    if (t == 31) asm volatile("s_waitcnt vmcnt(0)\n\ts_barrier" ::: "memory");
    else         asm volatile("s_waitcnt vmcnt(6)\n\ts_barrier" ::: "memory");
    if (t < 30) {
      int kk = (t + 2) * 32;
      int bo = ((t + 2) % 3) * 12288;
      u16* dA = sAB + bo + w * 1024;
      gload16(gA + kk, dA); gload16(gA + 16 * DIM + kk, dA + 512);
      u16* dB = sAB + bo + 4096 + w * 2048;
      gload16(gB + kk, dB); gload16(gB + 16 * DIM + kk, dB + 512);
      gload16(gB + 32 * DIM + kk, dB + 1024); gload16(gB + 48 * DIM + kk, dB + 1536);
    }
    const u16* cb = sAB + (t % 3) * 12288;
    short8 a[4], bb[8];
#pragma unroll
    for (int mi = 0; mi < 4; ++mi)
      a[mi] = *(const short8*)&cb[arb + mi * 512];
#pragma unroll
    for (int ni = 0; ni < 8; ++ni)
      bb[ni] = *(const short8*)&cb[brb + ni * 512];
#pragma unroll
    for (int mi = 0; mi < 4; ++mi)
#pragma unroll
      for (int ni = 0; ni < 8; ++ni)
        acc[mi][ni] = __builtin_amdgcn_mfma_f32_16x16x32_bf16(a[mi], bb[ni], acc[mi][ni], 0, 0, 0);
  }

  // ---- LoRA + bias as one extra K=32 MFMA step ----
  // A-lora: buf0.A = [2*xag | 1@k16] (for wn=0), buf1.A = [2*xau | 1@k16] (wn=1)
  // B-lora: buf0.B rows 0-127 = B_gate+bias, rows 128-255 = B_up+bias
  __syncthreads();
  {
    int rl = tid & 127, half = tid >> 7;
    int sw = (rl >> 1) & 3;
    int abase = half * 12288 + rl * 32;
    u16 tmp[16];
#pragma unroll
    for (int q = 0; q < 16; ++q) tmp[q] = f2bf(2.f * xagu[(size_t)(row0 + rl) * 32 + half * 16 + q]);
    *(u16x8*)&sAB[abase + (0 ^ sw) * 8] = *(u16x8*)&tmp[0];
    *(u16x8*)&sAB[abase + (1 ^ sw) * 8] = *(u16x8*)&tmp[8];
    u16 t2[8] = {0x3f80, 0, 0, 0, 0, 0, 0, 0};
    u16 t3[8] = {0, 0, 0, 0, 0, 0, 0, 0};
    *(u16x8*)&sAB[abase + (2 ^ sw) * 8] = *(u16x8*)&t2[0];
    *(u16x8*)&sAB[abase + (3 ^ sw) * 8] = *(u16x8*)&t3[0];
    // B-lora: one row per thread
    int r = tid, fb = r & 127, bh = r >> 7;
    int swb = (r >> 1) & 3;
    int bbase = 4096 + r * 32;
    const float* Bsrc = bh ? Bu : Bg;
    float bias = gub[e * 4096 + (bh ? (2048 + f0 + fb) : (f0 + fb))];
    u16 tb[16];
#pragma unroll
    for (int q = 0; q < 16; ++q) tb[q] = f2bf(Bsrc[((size_t)e * FFD + f0 + fb) * 16 + q]);
    *(u16x8*)&sAB[bbase + (0 ^ swb) * 8] = *(u16x8*)&tb[0];
    *(u16x8*)&sAB[bbase + (1 ^ swb) * 8] = *(u16x8*)&tb[8];
    u16 t2b[8] = {f2bf(bias), 0, 0, 0, 0, 0, 0, 0};
    *(u16x8*)&sAB[bbase + (2 ^ swb) * 8] = *(u16x8*)&t2b[0];
    *(u16x8*)&sAB[bbase + (3 ^ swb) * 8] = *(u16x8*)&t3[0];
  }
  __syncthreads();
  {
    int aBase = wn ? 12288 : 0;
    short8 a[4], bb[8];
#pragma unroll
    for (int mi = 0; mi < 4; ++mi)
      a[mi] = *(const short8*)&sAB[aBase + arb + mi * 512];
#pragma unroll
    for (int ni = 0; ni < 8; ++ni)
      bb[ni] = *(const short8*)&sAB[brb + ni * 512];
#pragma unroll
    for (int mi = 0; mi < 4; ++mi)
#pragma unroll
      for (int ni = 0; ni < 8; ++ni)
        acc[mi][ni] = __builtin_amdgcn_mfma_f32_16x16x32_bf16(a[mi], bb[ni], acc[mi][ni], 0, 0, 0);
  }
  // ---- SwiGLU via LDS exchange: sOut[128][256] bf16, XOR bank-swizzled ----
  __syncthreads();
#pragma unroll
  for (int mi = 0; mi < 4; ++mi)
#pragma unroll
    for (int ni = 0; ni < 8; ++ni)
#pragma unroll
      for (int j = 0; j < 4; ++j) {
        int row = wm * 64 + mi * 16 + (lane >> 4) * 4 + j;
        int br = wn * 128 + ni * 16 + (lane & 15);
        int key = ((row & 3) ^ ((row >> 2) & 3)) << 4;
        sAB[row * 256 + (br ^ key)] = f2bf(acc[mi][ni][j]);
      }
  __syncthreads();
  {
    int fc = (tid & 15) * 8;
    int rb = tid >> 4;
#pragma unroll
    for (int it = 0; it < 8; ++it) {
      int row = rb + it * 16;
      int key = ((row & 3) ^ ((row >> 2) & 3)) << 4;
      u16x8 gv = *(const u16x8*)&sAB[row * 256 + (fc ^ key)];
      u16x8 uv = *(const u16x8*)&sAB[row * 256 + ((fc + 128) ^ key)];
      u16x8 ov;
#pragma unroll
      for (int j = 0; j < 8; ++j) {
        float g = bf2f(gv[j]);
        float u = bf2f(uv[j]);
        float s = g / (1.f + __expf(-g));
        ov[j] = f2bf(s * u);
      }
      *(u16x8*)(act + (size_t)(row0 + row) * FFD + f0 + fc) = ov;
    }
  }
}

// ------- GEMM2: down = act@Wd + b + lora; 128x256 tile, split-K=2 -----------
__global__ __launch_bounds__(256, 2) void gemm2_k(
    const u16* __restrict__ act, const u16* __restrict__ wd_t,
    const float* __restrict__ db, const float* __restrict__ Bd,
    const float* __restrict__ aad, const int* __restrict__ offs,
    u16* __restrict__ down) {
  __shared__ __align__(16) u16 sAB[36864];
  int tid = threadIdx.x, w = tid >> 6, lane = tid & 63;
  int n0 = blockIdx.x * 256;
  int row0 = blockIdx.y * 128;
  int ks = blockIdx.z;
  size_t kbase = (size_t)ks * 1024;
  int e = 0;
  if (row0 >= offs[1]) e = 1;
  if (row0 >= offs[2]) e = 2;
  if (row0 >= offs[3]) e = 3;
  int wm = w >> 1, wn = w & 1;

  int srow = lane >> 2;
  int scol = ((lane & 3) ^ ((lane >> 3) & 3)) * 8;
  const u16* gA = act + (size_t)(row0 + w * 32 + srow) * FFD + kbase + scol;
  const u16* gB = wd_t + (size_t)e * DIM * FFD + (size_t)(n0 + w * 64 + srow) * FFD + kbase + scol;
  int fo = (((lane >> 4) ^ ((lane >> 1) & 3))) * 8;
  int arb = (wm * 64 + (lane & 15)) * 32 + fo;
  int brb = 4096 + (wn * 128 + (lane & 15)) * 32 + fo;

  f32x4 acc[4][8];
#pragma unroll
  for (int i = 0; i < 4; ++i)
#pragma unroll
    for (int j = 0; j < 8; ++j) acc[i][j] = f32x4{0.f, 0.f, 0.f, 0.f};

#pragma unroll
  for (int p = 0; p < 2; ++p) {
    u16* dA = sAB + p * 12288 + w * 1024;
    gload16(gA + p * 32, dA); gload16(gA + 16 * FFD + p * 32, dA + 512);
    u16* dB = sAB + p * 12288 + 4096 + w * 2048;
    gload16(gB + p * 32, dB); gload16(gB + 16 * FFD + p * 32, dB + 512);
    gload16(gB + 32 * FFD + p * 32, dB + 1024); gload16(gB + 48 * FFD + p * 32, dB + 1536);
  }
#pragma unroll
  for (int t = 0; t < 32; ++t) {
    if (t == 31) asm volatile("s_waitcnt vmcnt(0)\n\ts_barrier" ::: "memory");
    else         asm volatile("s_waitcnt vmcnt(6)\n\ts_barrier" ::: "memory");
    if (t < 30) {
      int kk = (t + 2) * 32;
      int bo = ((t + 2) % 3) * 12288;
      u16* dA = sAB + bo + w * 1024;
      gload16(gA + kk, dA); gload16(gA + 16 * FFD + kk, dA + 512);
      u16* dB = sAB + bo + 4096 + w * 2048;
      gload16(gB + kk, dB); gload16(gB + 16 * FFD + kk, dB + 512);
      gload16(gB + 32 * FFD + kk, dB + 1024); gload16(gB + 48 * FFD + kk, dB + 1536);
    }
    const u16* cb = sAB + (t % 3) * 12288;
    short8 a[4], bb[8];
#pragma unroll
    for (int mi = 0; mi < 4; ++mi)
      a[mi] = *(const short8*)&cb[arb + mi * 512];
#pragma unroll
    for (int ni = 0; ni < 8; ++ni)
      bb[ni] = *(const short8*)&cb[brb + ni * 512];
#pragma unroll
    for (int mi = 0; mi < 4; ++mi)
#pragma unroll
      for (int ni = 0; ni < 8; ++ni)
        acc[mi][ni] = __builtin_amdgcn_mfma_f32_16x16x32_bf16(a[mi], bb[ni], acc[mi][ni], 0, 0, 0);
  }

  if (ks == 0) {
    // ---- LoRA-down + bias as one extra K=32 MFMA step ----
    __syncthreads();
    {
      int r = tid >> 1, kh = tid & 1;
      int sw = (r >> 1) & 3;
      int o0 = r * 32 + ((2 * kh + 0) ^ sw) * 8;
      int o1 = r * 32 + ((2 * kh + 1) ^ sw) * 8;
      u16 tmp[16];
      if (kh == 0) {
#pragma unroll
        for (int q = 0; q < 16; ++q) tmp[q] = f2bf(2.f * aad[(size_t)(row0 + r) * 16 + q]);
      } else {
#pragma unroll
        for (int q = 0; q < 16; ++q) tmp[q] = 0;
        tmp[0] = 0x3f80;
      }
      *(u16x8*)&sAB[o0] = *(u16x8*)&tmp[0];
      *(u16x8*)&sAB[o1] = *(u16x8*)&tmp[8];
      // B-lora: one row per thread (256 rows)
      int r2 = tid;
      int swb = (r2 >> 1) & 3;
      int bbase = 4096 + r2 * 32;
      u16 tb[16];
#pragma unroll
      for (int q = 0; q < 16; ++q) tb[q] = f2bf(Bd[((size_t)e * DIM + n0 + r2) * 16 + q]);
      *(u16x8*)&sAB[bbase + (0 ^ swb) * 8] = *(u16x8*)&tb[0];
      *(u16x8*)&sAB[bbase + (1 ^ swb) * 8] = *(u16x8*)&tb[8];
      u16 t2b[8] = {f2bf(db[e * DIM + n0 + r2]), 0, 0, 0, 0, 0, 0, 0};
      u16 t3b[8] = {0, 0, 0, 0, 0, 0, 0, 0};
      *(u16x8*)&sAB[bbase + (2 ^ swb) * 8] = *(u16x8*)&t2b[0];
      *(u16x8*)&sAB[bbase + (3 ^ swb) * 8] = *(u16x8*)&t3b[0];
    }
    __syncthreads();
    {
      short8 a[4], bb[8];
#pragma unroll
      for (int mi = 0; mi < 4; ++mi)
        a[mi] = *(const short8*)&sAB[arb + mi * 512];
#pragma unroll
      for (int ni = 0; ni < 8; ++ni)
        bb[ni] = *(const short8*)&sAB[brb + ni * 512];
#pragma unroll
      for (int mi = 0; mi < 4; ++mi)
#pragma unroll
        for (int ni = 0; ni < 8; ++ni)
          acc[mi][ni] = __builtin_amdgcn_mfma_f32_16x16x32_bf16(a[mi], bb[ni], acc[mi][ni], 0, 0, 0);
    }
  }
  // ---- store bf16 partial ----
#pragma unroll
  for (int mi = 0; mi < 4; ++mi)
#pragma unroll
    for (int ni = 0; ni < 8; ++ni)
#pragma unroll
      for (int j = 0; j < 4; ++j) {
        int lr = wm * 64 + mi * 16 + (lane >> 4) * 4 + j;
        int lc = wn * 128 + ni * 16 + (lane & 15);
        down[((size_t)ks * NRP + row0 + lr) * DIM + n0 + lc] = f2bf(acc[mi][ni][j]);
      }
}

// ---------------- weighted combine (sums split-K halves) --------------------
__global__ void combine_k(const u16* __restrict__ down, const int* __restrict__ pairrow,
                          const float* __restrict__ selw, float* __restrict__ out) {
  int t = blockIdx.x, tid = threadIdx.x;   // 256 threads, 4 cols each
  int r0 = pairrow[2 * t], r1 = pairrow[2 * t + 1];
  float w0 = selw[2 * t], w1 = selw[2 * t + 1];
  u16x4 a0 = *(const u16x4*)(down + ((size_t)r0) * DIM + tid * 4);
  u16x4 a1 = *(const u16x4*)(down + ((size_t)NRP + r0) * DIM + tid * 4);
  u16x4 b0 = *(const u16x4*)(down + ((size_t)r1) * DIM + tid * 4);
  u16x4 b1 = *(const u16x4*)(down + ((size_t)NRP + r1) * DIM + tid * 4);
  f32x4 o;
#pragma unroll
  for (int j = 0; j < 4; ++j)
    o[j] = w0 * (bf2f(a0[j]) + bf2f(a1[j])) + w1 * (bf2f(b0[j]) + bf2f(b1[j]));
  *(f32x4*)(out + (size_t)t * DIM + tid * 4) = o;
}

extern "C" void kernel_launch(void* const* d_in, const int* in_sizes, int n_in,
                              void* d_out, int out_size, void* d_ws, size_t ws_size,
                              hipStream_t stream) {
  const float* x         = (const float*)d_in[0];
  const float* gate_w    = (const float*)d_in[1];
  const float* gate_up_w = (const float*)d_in[2];
  const float* gate_up_b = (const float*)d_in[3];
  const float* down_w    = (const float*)d_in[4];
  const float* down_b    = (const float*)d_in[5];
  const float* A_gate    = (const float*)d_in[6];
  const float* B_gate    = (const float*)d_in[7];
  const float* A_up      = (const float*)d_in[8];
  const float* B_up      = (const float*)d_in[9];
  const float* A_down    = (const float*)d_in[10];
  const float* B_down    = (const float*)d_in[11];

  float* out_final  = (float*)d_out;
  float* out_logits = out_final + (size_t)T_TOK * DIM;

  char* ws = (char*)d_ws;
  size_t o = 0;
  auto take = [&](size_t bytes) -> void* {
    void* p = ws + o;
    o = (o + bytes + 255) & ~(size_t)255;
    return p;
  };
  int*   offs    = (int*)take(64);
  int*   sel     = (int*)take((size_t)T_TOK * 2 * 4);
  float* selw    = (float*)take((size_t)T_TOK * 2 * 4);
  int*   pos     = (int*)take((size_t)T_TOK * 2 * 4);
  int*   pairrow = (int*)take((size_t)T_TOK * 2 * 4);
  int*   rowtok  = (int*)take((size_t)NRP * 4);
  float* xagu    = (float*)take((size_t)NRP * 32 * 4);
  float* aadb    = (float*)take((size_t)NRP * 16 * 4);
  u16*   abgu    = (u16*)take((size_t)NEXP * 32 * DIM * 2);
  u16*   adb     = (u16*)take((size_t)NEXP * 16 * FFD * 2);
  u16*   xg      = (u16*)take((size_t)NRP * DIM * 2);
  u16*   actb    = (u16*)take((size_t)NRP * FFD * 2);
  u16*   downb   = (u16*)take((size_t)2 * NRP * DIM * 2);
  u16*   wgu_t   = (u16*)take((size_t)NEXP * 2 * FFD * DIM * 2);
  u16*   wd_t    = (u16*)take((size_t)NEXP * DIM * FFD * 2);
  (void)ws_size; (void)in_sizes; (void)n_in; (void)out_size;

  // weight transposes (fp32 [K][N] -> bf16 [N][K]) — independent of routing
  transpose_k<<<dim3(128, 32, NEXP), dim3(32, 8), 0, stream>>>(gate_up_w, wgu_t, DIM, 2 * FFD);
  transpose_k<<<dim3(32, 64, NEXP), dim3(32, 8), 0, stream>>>(down_w, wd_t, FFD, DIM);
  cvtA_k<<<256, 256, 0, stream>>>(A_gate, A_up, A_down, abgu, adb);

  router_k<<<T_TOK, 64, 0, stream>>>(x, gate_w, out_logits, sel, selw);
  scan_k<<<1, 1024, 0, stream>>>(sel, pos, offs, rowtok, pairrow);
  gatherxa_k<<<NRP / 2, 64, 0, stream>>>(x, rowtok, abgu, offs, xg, xagu);
  gemm1_k<<<dim3(16, MTILES), 256, 0, stream>>>(xg, wgu_t, gate_up_b, B_gate, B_up,
                                                xagu, offs, actb);
  aad_k<<<NRP / 2, 64, 0, stream>>>(actb, adb, offs, aadb);
  gemm2_k<<<dim3(4, MTILES, 2), 256, 0, stream>>>(actb, wd_t, down_b, B_down, aadb, offs, downb);
  combine_k<<<T_TOK, 256, 0, stream>>>(downb, pairrow, selw, out_final);
}